// Round 3
// baseline (298.287 us; speedup 1.0000x reference)
//
#include <hip/hip_runtime.h>
#include <hip/hip_fp16.h>
#include <hip/hip_cooperative_groups.h>
#include <math.h>

namespace cg = cooperative_groups;

// ---------------------------------------------------------------------------
// GCN 2-layer + two heads, fp32 in/out, MI355X.
//   R8: fixed-capacity slab partition (no histogram pass, no scans in
//   partition), cooperative fusion of {partition -> CSR} with gemm0 blocks
//   (one dispatch, latency-bound blocks co-resident with MFMA blocks),
//   inline W staging fp32->split-bf16 (prep kernel gone), single-X-pass
//   heads. 6 dispatches total (memset, coop, agg0, gemm1, agg1, heads).
// ---------------------------------------------------------------------------

#define DFEAT 128
#define BSH 8            // bucket = dst >> 8 (256 nodes/bucket)
#define BKE 4096         // edges per partition block
#define SLABCAP 4608     // bucket slab capacity: mean 4096 + 8 sigma

using short8  = __attribute__((ext_vector_type(8))) short;
using floatx4 = __attribute__((ext_vector_type(4))) float;

__device__ __forceinline__ unsigned short f2bf_rne(float x) {
    unsigned u = __float_as_uint(x);
    unsigned r = u + 0x7FFFu + ((u >> 16) & 1u);
    return (unsigned short)(r >> 16);
}

// --------- W staging: fp32 -> split-bf16 MFMA fragment layout in LDS --------
__device__ __forceinline__ void stage_W(const float* __restrict__ W,
                                        short* __restrict__ WhiS,
                                        short* __restrict__ WloS) {
    const int tid = threadIdx.x;
#pragma unroll
    for (int it = 0; it < 16; ++it) {
        int e = (it * 256 + tid) * 4;           // element (k,n) = (e>>7, e&127)
        float4 wv = *(const float4*)(W + e);
        int k = e >> 7, n0 = e & 127;
        float vals[4] = {wv.x, wv.y, wv.z, wv.w};
        int s = k >> 5, quad = (k >> 3) & 3, j = k & 7;
#pragma unroll
        for (int q = 0; q < 4; ++q) {
            int n = n0 + q;
            int t = n >> 4, l16 = n & 15;
            int i = ((t * 4 + s) << 9) + (((quad << 4) + l16) << 3) + j;
            unsigned short h = f2bf_rne(vals[q]);
            WhiS[i] = (short)h;
            WloS[i] = (short)f2bf_rne(vals[q] - __uint_as_float(((unsigned)h) << 16));
        }
    }
}

// --------------------- A-fragment load + split-bf16 convert -----------------
template <typename InT>
__device__ __forceinline__ void load_A(const InT* __restrict__ X, int M, int m0,
                                       short8 (&Ahi)[2][4], short8 (&Alo)[2][4]) {
    const int lane = threadIdx.x & 63;
    const int quad = lane >> 4, l16 = lane & 15;
#pragma unroll
    for (int r = 0; r < 2; ++r) {
        int row = m0 + r * 16 + l16;
        row = row < M ? row : (M - 1);
        const InT* xr = X + (size_t)row * 128 + quad * 8;
#pragma unroll
        for (int s = 0; s < 4; ++s) {
            float v[8];
            if constexpr (sizeof(InT) == 4) {
                float4 a = ((const float4*)(xr + s * 32))[0];
                float4 b = ((const float4*)(xr + s * 32))[1];
                v[0] = a.x; v[1] = a.y; v[2] = a.z; v[3] = a.w;
                v[4] = b.x; v[5] = b.y; v[6] = b.z; v[7] = b.w;
            } else {
                uint4 raw = *(const uint4*)(xr + s * 32);
                const __half2* hp = (const __half2*)&raw;
#pragma unroll
                for (int k = 0; k < 4; ++k) {
                    float2 f = __half22float2(hp[k]);
                    v[2 * k] = f.x; v[2 * k + 1] = f.y;
                }
            }
#pragma unroll
            for (int j = 0; j < 8; ++j) {
                unsigned short h = f2bf_rne(v[j]);
                Ahi[r][s][j] = (short)h;
                Alo[r][s][j] = (short)f2bf_rne(v[j] - __uint_as_float(((unsigned)h) << 16));
            }
        }
    }
}

// ----------------------- MFMA compute + epilogue ----------------------------
template <typename OutT, bool BIAS, bool RELU>
__device__ __forceinline__ void mfma_store(short8 (&Ahi)[2][4], short8 (&Alo)[2][4],
                                           const short* __restrict__ WhiS,
                                           const short* __restrict__ WloS,
                                           const float* __restrict__ bias,
                                           OutT* __restrict__ Y, int M, int m0) {
    const int lane = threadIdx.x & 63;
    const int quad = lane >> 4, l16 = lane & 15;

    floatx4 acc[2][8];
#pragma unroll
    for (int r = 0; r < 2; ++r)
#pragma unroll
        for (int t = 0; t < 8; ++t) acc[r][t] = (floatx4){0.f, 0.f, 0.f, 0.f};

    const short8* WH = (const short8*)WhiS;
    const short8* WL = (const short8*)WloS;
#pragma unroll
    for (int s = 0; s < 4; ++s) {
#pragma unroll
        for (int t = 0; t < 8; ++t) {
            short8 bh = WH[(t * 4 + s) * 64 + lane];
            short8 bl = WL[(t * 4 + s) * 64 + lane];
#pragma unroll
            for (int r = 0; r < 2; ++r) {
                acc[r][t] = __builtin_amdgcn_mfma_f32_16x16x32_bf16(Ahi[r][s], bh, acc[r][t], 0, 0, 0);
                acc[r][t] = __builtin_amdgcn_mfma_f32_16x16x32_bf16(Alo[r][s], bh, acc[r][t], 0, 0, 0);
                acc[r][t] = __builtin_amdgcn_mfma_f32_16x16x32_bf16(Ahi[r][s], bl, acc[r][t], 0, 0, 0);
            }
        }
    }

    float bcol[8];
    if (BIAS) {
#pragma unroll
        for (int t = 0; t < 8; ++t) bcol[t] = bias[t * 16 + l16];
    }
#pragma unroll
    for (int r = 0; r < 2; ++r) {
#pragma unroll
        for (int e = 0; e < 4; ++e) {
            int row = m0 + r * 16 + quad * 4 + e;
            if (row < M) {
                OutT* yr = Y + (size_t)row * 128 + l16;
#pragma unroll
                for (int t = 0; t < 8; ++t) {
                    float v = acc[r][t][e];
                    if (BIAS) v += bcol[t];
                    if (RELU) v = fmaxf(v, 0.f);
                    if constexpr (sizeof(OutT) == 4) yr[t * 16] = v;
                    else yr[t * 16] = __float2half(v);
                }
            }
        }
    }
}

template <typename InT, typename OutT, bool BIAS, bool RELU>
__device__ __forceinline__ void gemm_core(const InT* __restrict__ X,
                                          const float* __restrict__ W,
                                          const float* __restrict__ bias,
                                          OutT* __restrict__ Y, int M, int blk,
                                          short* WhiS, short* WloS, bool doStage) {
    if (doStage) stage_W(W, WhiS, WloS);
    short8 Ahi[2][4], Alo[2][4];
    int m0 = blk * 128 + ((threadIdx.x >> 6) << 5);
    load_A<InT>(X, M, m0, Ahi, Alo);
    __syncthreads();
    mfma_store<OutT, BIAS, RELU>(Ahi, Alo, WhiS, WloS, bias, Y, M, m0);
}

// ---------------- partition: edges -> fixed-capacity bucket slabs -----------
__device__ __forceinline__ void partition_body(const int* __restrict__ src,
                                               const int* __restrict__ dst,
                                               int* __restrict__ cursor,
                                               unsigned* __restrict__ pk_out,
                                               int E, int nbuk, int B) {
    __shared__ int h[256];
    __shared__ int base[256];
    int tid = threadIdx.x;
    h[tid] = 0;
    __syncthreads();
    int e0 = B * BKE;

    unsigned pk[16];
    unsigned short rk[16];
    unsigned char bk[16];
    int m = 0;
#pragma unroll
    for (int it = 0; it < 4; ++it) {
        int e = e0 + it * 1024 + tid * 4;
        if (e + 3 < E) {
            int4 d4 = *(const int4*)(dst + e);
            int4 s4 = *(const int4*)(src + e);
            int dd[4] = {d4.x, d4.y, d4.z, d4.w};
            int ss[4] = {s4.x, s4.y, s4.z, s4.w};
#pragma unroll
            for (int k = 0; k < 4; ++k) {
                int b = dd[k] >> BSH;
                pk[m] = ((unsigned)dd[k] << 16) | (unsigned)ss[k];
                rk[m] = (unsigned short)atomicAdd(&h[b], 1);
                bk[m] = (unsigned char)b;
                ++m;
            }
        } else {
            for (int k = 0; k < 4; ++k) {
                if (e + k < E) {
                    int d = dst[e + k], sv = src[e + k];
                    int b = d >> BSH;
                    pk[m] = ((unsigned)d << 16) | (unsigned)sv;
                    rk[m] = (unsigned short)atomicAdd(&h[b], 1);
                    bk[m] = (unsigned char)b;
                    ++m;
                }
            }
        }
    }
    __syncthreads();
    if (tid < nbuk && h[tid]) base[tid] = tid * SLABCAP + atomicAdd(&cursor[tid], h[tid]);
    __syncthreads();
    for (int j = 0; j < m; ++j)
        pk_out[base[bk[j]] + (int)rk[j]] = pk[j];
}

// ---------------- CSR build from slabs (counts in cursor) -------------------
__device__ __forceinline__ void csr_body(const unsigned* __restrict__ pk_arr,
                                         const int* __restrict__ cursor,
                                         int* __restrict__ row_ptr,
                                         unsigned short* __restrict__ col_idx,
                                         float* __restrict__ dinv,
                                         int N, int E, int nbuk, int b) {
    __shared__ int hcnt[256];
    __shared__ int esc[256];
    __shared__ int sx[256];
    int tid = threadIdx.x;

    // exclusive prefix over bucket counts -> compacted base s0
    int v = (tid < nbuk) ? cursor[tid] : 0;
    sx[tid] = v;
    __syncthreads();
    int x = v;
    for (int o = 1; o < 256; o <<= 1) {
        int y = (tid >= o) ? sx[tid - o] : 0;
        __syncthreads();
        x += y;
        sx[tid] = x;
        __syncthreads();
    }
    int s0 = (b > 0) ? sx[b - 1] : 0;
    int cnt = sx[b] - s0;
    __syncthreads();

    hcnt[tid] = 0;
    __syncthreads();

    const unsigned* slab = pk_arr + (size_t)b * SLABCAP;
    unsigned p[20];
    unsigned short r[20];
    int m = 0;
    for (int i = tid; i < cnt; i += 256) {
        unsigned pp = slab[i];
        int d = (pp >> 16) & 255;
        r[m] = (unsigned short)atomicAdd(&hcnt[d], 1);
        p[m] = pp;
        ++m;
    }
    __syncthreads();

    int hv = hcnt[tid];
    esc[tid] = hv;
    __syncthreads();
    int hx = hv;
    for (int o = 1; o < 256; o <<= 1) {
        int y = (tid >= o) ? esc[tid - o] : 0;
        __syncthreads();
        hx += y;
        esc[tid] = hx;
        __syncthreads();
    }
    int excl = hx - hv;
    __syncthreads();
    esc[tid] = excl;
    __syncthreads();

    int node = (b << BSH) + tid;
    if (node < N) {
        row_ptr[node] = s0 + excl;
        dinv[node] = rsqrtf((float)(hv + 1));   // +1 self loop
    }
    if (node == N) row_ptr[N] = E;

    for (int j = 0; j < m; ++j) {
        int d = (p[j] >> 16) & 255;
        col_idx[s0 + esc[d] + (int)r[j]] = (unsigned short)(p[j] & 0xFFFFu);
    }
}

// ---------------- cooperative fused dispatch --------------------------------
// blocks [0,npb): partition -> (grid sync) -> CSR build
// blocks [npb,G): gemm0 tiles (window 0 before sync, leftovers after)
__global__ __launch_bounds__(256) void coop_k(const int* __restrict__ src,
                                              const int* __restrict__ dst,
                                              int* __restrict__ cursor,
                                              unsigned* __restrict__ pk_arr,
                                              int* __restrict__ row_ptr,
                                              unsigned short* __restrict__ col_idx,
                                              float* __restrict__ dinv,
                                              const float* __restrict__ X,
                                              const float* __restrict__ W0,
                                              __half* __restrict__ hs,
                                              int N, int E, int nbuk, int npb, int gb) {
    __shared__ short WhiS[16384];
    __shared__ short WloS[16384];
    int B = blockIdx.x, G = gridDim.x;
    int ng = G - npb;

    if (B < npb) {
        partition_body(src, dst, cursor, pk_arr, E, nbuk, B);
    } else {
        int t = B - npb;
        if (t < gb)
            gemm_core<float, __half, false, false>(X, W0, nullptr, hs, N, t, WhiS, WloS, true);
    }

    cg::this_grid().sync();

    if (B < nbuk) {
        csr_body(pk_arr, cursor, row_ptr, col_idx, dinv, N, E, nbuk, B);
    } else if (B >= npb) {
        int t = B - npb + ng;
        while (t < gb) {
            gemm_core<float, __half, false, false>(X, W0, nullptr, hs, N, t, WhiS, WloS, false);
            t += ng;
        }
    }
}

// ---------------- non-coop fallbacks ----------------------------------------
__global__ __launch_bounds__(256) void partition_k(const int* __restrict__ src,
                                                   const int* __restrict__ dst,
                                                   int* __restrict__ cursor,
                                                   unsigned* __restrict__ pk_arr,
                                                   int E, int nbuk) {
    partition_body(src, dst, cursor, pk_arr, E, nbuk, blockIdx.x);
}

__global__ __launch_bounds__(256) void csrgemm_k(const unsigned* __restrict__ pk_arr,
                                                 const int* __restrict__ cursor,
                                                 int* __restrict__ row_ptr,
                                                 unsigned short* __restrict__ col_idx,
                                                 float* __restrict__ dinv,
                                                 const float* __restrict__ X,
                                                 const float* __restrict__ W0,
                                                 __half* __restrict__ hs,
                                                 int N, int E, int nbuk) {
    __shared__ short WhiS[16384];
    __shared__ short WloS[16384];
    if ((int)blockIdx.x < nbuk) {
        csr_body(pk_arr, cursor, row_ptr, col_idx, dinv, N, E, nbuk, blockIdx.x);
        return;
    }
    gemm_core<float, __half, false, false>(X, W0, nullptr, hs, N, blockIdx.x - nbuk,
                                           WhiS, WloS, true);
}

// ---------------- standalone GEMM (layer 1) ---------------------------------
template <typename InT, typename OutT, bool BIAS, bool RELU>
__global__ __launch_bounds__(256) void gemm_k(const InT* __restrict__ X,
                                              const float* __restrict__ W,
                                              const float* __restrict__ bias,
                                              OutT* __restrict__ Y, int M) {
    __shared__ short WhiS[16384];
    __shared__ short WloS[16384];
    gemm_core<InT, OutT, BIAS, RELU>(X, W, bias, Y, M, blockIdx.x, WhiS, WloS, true);
}

// ---------------- heads: both GEMMs, one pass over X ------------------------
__global__ __launch_bounds__(256) void heads_k(const float* __restrict__ X,
                                               const float* __restrict__ Wv,
                                               const float* __restrict__ bv,
                                               const float* __restrict__ Wt,
                                               const float* __restrict__ bt,
                                               float* __restrict__ Yv,
                                               float* __restrict__ Yt, int M) {
    __shared__ short WhiS[16384];
    __shared__ short WloS[16384];
    short8 Ahi[2][4], Alo[2][4];
    int m0 = blockIdx.x * 128 + ((threadIdx.x >> 6) << 5);
    stage_W(Wv, WhiS, WloS);
    load_A<float>(X, M, m0, Ahi, Alo);
    __syncthreads();
    mfma_store<float, true, true>(Ahi, Alo, WhiS, WloS, bv, Yv, M, m0);
    __syncthreads();                 // all reads of Wv done
    stage_W(Wt, WhiS, WloS);
    __syncthreads();
    mfma_store<float, true, true>(Ahi, Alo, WhiS, WloS, bt, Yt, M, m0);
}

// ----------------------------- Aggregates -----------------------------------
// layer 0: h0 table UNSCALED; gathers dinv[col] as edge weight;
// out = dinv_i * relu(dinv_i * acc + b0)  (pre-scaled for layer-1 GEMM).
__global__ __launch_bounds__(256) void agg0_k(const __half* __restrict__ hs,
                                              const int* __restrict__ row_ptr,
                                              const unsigned short* __restrict__ col_idx,
                                              const float* __restrict__ dinv,
                                              const float* __restrict__ bias,
                                              __half* __restrict__ out, int n) {
    const int c = threadIdx.x & 15;
    const int gbase = threadIdx.x & 48;
    int grp = blockIdx.x * 16 + (threadIdx.x >> 4);
    int ngrp = gridDim.x * 16;

    float4 b0 = ((const float4*)bias)[c * 2];
    float4 b1 = ((const float4*)bias)[c * 2 + 1];

    for (int i = grp; i < n; i += ngrp) {
        float di = dinv[i];
        float acc[8];
        {
            uint4 raw = ((const uint4*)(hs + (size_t)i * DFEAT))[c];
            const __half2* hp = (const __half2*)&raw;
#pragma unroll
            for (int k = 0; k < 4; ++k) {
                float2 f = __half22float2(hp[k]);
                acc[2 * k] = f.x * di; acc[2 * k + 1] = f.y * di;
            }
        }
        int s = row_ptr[i];
        int cnt = row_ptr[i + 1] - s;

        for (int base = 0; base < cnt; base += 16) {
            int t = base + c;
            int idx = (t < cnt) ? (int)col_idx[s + t] : 0;
            float dv = (t < cnt) ? dinv[idx] : 0.f;
            int lim = cnt - base; if (lim > 16) lim = 16;
            uint4 vv[16];
#pragma unroll
            for (int q = 0; q < 16; ++q) {
                int ia = __shfl(idx, gbase + q);
                if (q < lim)
                    vv[q] = ((const uint4*)(hs + (size_t)ia * DFEAT))[c];
            }
            float w[16];
#pragma unroll
            for (int q = 0; q < 16; ++q) w[q] = __shfl(dv, gbase + q);
#pragma unroll
            for (int q = 0; q < 16; ++q) {
                if (q < lim) {
                    const __half2* pq = (const __half2*)&vv[q];
#pragma unroll
                    for (int k = 0; k < 4; ++k) {
                        float2 f = __half22float2(pq[k]);
                        acc[2 * k]     = fmaf(f.x, w[q], acc[2 * k]);
                        acc[2 * k + 1] = fmaf(f.y, w[q], acc[2 * k + 1]);
                    }
                }
            }
        }

        float o[8];
        o[0] = fmaf(acc[0], di, b0.x); o[1] = fmaf(acc[1], di, b0.y);
        o[2] = fmaf(acc[2], di, b0.z); o[3] = fmaf(acc[3], di, b0.w);
        o[4] = fmaf(acc[4], di, b1.x); o[5] = fmaf(acc[5], di, b1.y);
        o[6] = fmaf(acc[6], di, b1.z); o[7] = fmaf(acc[7], di, b1.w);
#pragma unroll
        for (int k = 0; k < 8; ++k) o[k] = fmaxf(o[k], 0.f) * di;  // h1' = di*relu

        __half2 hpk[4];
#pragma unroll
        for (int k = 0; k < 4; ++k)
            hpk[k] = __floats2half2_rn(o[2 * k], o[2 * k + 1]);
        ((uint4*)((__half*)out + (size_t)i * DFEAT))[c] = *(uint4*)hpk;
    }
}

// layer 1: table pre-scaled -> unweighted gather; out = dinv_i*acc + b1 (fp32)
__global__ __launch_bounds__(256) void agg1_k(const __half* __restrict__ hs,
                                              const int* __restrict__ row_ptr,
                                              const unsigned short* __restrict__ col_idx,
                                              const float* __restrict__ dinv,
                                              const float* __restrict__ bias,
                                              float* __restrict__ out, int n) {
    const int c = threadIdx.x & 15;
    const int gbase = threadIdx.x & 48;
    int grp = blockIdx.x * 16 + (threadIdx.x >> 4);
    int ngrp = gridDim.x * 16;

    float4 b0 = ((const float4*)bias)[c * 2];
    float4 b1 = ((const float4*)bias)[c * 2 + 1];

    for (int i = grp; i < n; i += ngrp) {
        float acc[8];
        {
            uint4 raw = ((const uint4*)(hs + (size_t)i * DFEAT))[c];
            const __half2* hp = (const __half2*)&raw;
#pragma unroll
            for (int k = 0; k < 4; ++k) {
                float2 f = __half22float2(hp[k]);
                acc[2 * k] = f.x; acc[2 * k + 1] = f.y;
            }
        }
        int s = row_ptr[i];
        int cnt = row_ptr[i + 1] - s;

        for (int base = 0; base < cnt; base += 16) {
            int t = base + c;
            int idx = (t < cnt) ? (int)col_idx[s + t] : 0;
            int lim = cnt - base; if (lim > 16) lim = 16;
            uint4 vv[16];
#pragma unroll
            for (int q = 0; q < 16; ++q) {
                int ia = __shfl(idx, gbase + q);
                if (q < lim)
                    vv[q] = ((const uint4*)(hs + (size_t)ia * DFEAT))[c];
            }
#pragma unroll
            for (int q = 0; q < 16; ++q) {
                if (q < lim) {
                    const __half2* pq = (const __half2*)&vv[q];
#pragma unroll
                    for (int k = 0; k < 4; ++k) {
                        float2 f = __half22float2(pq[k]);
                        acc[2 * k]     += f.x;
                        acc[2 * k + 1] += f.y;
                    }
                }
            }
        }

        float di = dinv[i];
        float o[8];
        o[0] = fmaf(acc[0], di, b0.x); o[1] = fmaf(acc[1], di, b0.y);
        o[2] = fmaf(acc[2], di, b0.z); o[3] = fmaf(acc[3], di, b0.w);
        o[4] = fmaf(acc[4], di, b1.x); o[5] = fmaf(acc[5], di, b1.y);
        o[6] = fmaf(acc[6], di, b1.z); o[7] = fmaf(acc[7], di, b1.w);
        ((float4*)(out + (size_t)i * DFEAT))[c * 2] =
            make_float4(o[0], o[1], o[2], o[3]);
        ((float4*)(out + (size_t)i * DFEAT))[c * 2 + 1] =
            make_float4(o[4], o[5], o[6], o[7]);
    }
}

// ---------------------------------------------------------------------------

static inline size_t align_up(size_t x, size_t a) { return (x + a - 1) & ~(a - 1); }

extern "C" void kernel_launch(void* const* d_in, const int* in_sizes, int n_in,
                              void* d_out, int out_size, void* d_ws, size_t ws_size,
                              hipStream_t stream) {
    const float* x  = (const float*)d_in[0];
    const int*   ei = (const int*)d_in[1];
    const float* W0 = (const float*)d_in[2];
    const float* b0 = (const float*)d_in[3];
    const float* W1 = (const float*)d_in[4];
    const float* b1 = (const float*)d_in[5];
    const float* Wv = (const float*)d_in[6];
    const float* bv = (const float*)d_in[7];
    const float* Wt = (const float*)d_in[8];
    const float* bt = (const float*)d_in[9];

    const int N = in_sizes[0] / DFEAT;
    const int E = in_sizes[1] / 2;
    const int* src = ei;
    const int* dst = ei + E;
    const int nbuk = (N + 255) >> BSH;
    const int npb  = (E + BKE - 1) / BKE;
    const int gb   = (N + 127) / 128;
    const int aggB = (N + 15) / 16;

    // workspace carve-up
    char* w = (char*)d_ws;
    int* cursor      = (int*)w; w += align_up((size_t)256 * 4, 256);
    unsigned* pk_arr = (unsigned*)w; w += align_up((size_t)nbuk * SLABCAP * 4, 256);
    int* row_ptr     = (int*)w; w += align_up((size_t)(N + 1) * 4, 256);
    unsigned short* col_idx = (unsigned short*)w; w += align_up((size_t)E * 2, 256);
    float* dinv      = (float*)w; w += align_up((size_t)N * 4, 256);
    __half* hs       = (__half*)w; w += align_up((size_t)N * DFEAT * 2, 256);
    __half* h1       = (__half*)w; w += align_up((size_t)N * DFEAT * 2, 256);

    float* out_h = (float*)d_out;
    float* out_v = out_h + (size_t)N * DFEAT;
    float* out_t = out_h + 2 * (size_t)N * DFEAT;

    // one-time cooperative-grid sizing (host-side queries only; capture-safe)
    static int coopG = -2;
    if (coopG == -2) {
        int maxb = 0, dev = 0;
        hipError_t e1 = hipOccupancyMaxActiveBlocksPerMultiprocessor(&maxb, coop_k, 256, 0);
        hipGetDevice(&dev);
        hipDeviceProp_t prop{};
        hipError_t e2 = hipGetDeviceProperties(&prop, dev);
        if (e1 == hipSuccess && e2 == hipSuccess && maxb >= 1) {
            long g = (long)maxb * (long)prop.multiProcessorCount;
            long cap = (long)npb + (long)gb;
            coopG = (int)(g < cap ? g : cap);
        } else {
            coopG = -1;
        }
    }

    hipMemsetAsync(cursor, 0, 256 * 4, stream);

    bool coop_done = false;
    if (coopG >= npb + 196) {
        const int* sv = src; const int* dv = dst;
        int* cu = cursor; unsigned* pk = pk_arr;
        int* rp = row_ptr; unsigned short* ci = col_idx; float* di = dinv;
        const float* xv = x; const float* w0 = W0; __half* hv = hs;
        int Nv = N, Ev = E, nb = nbuk, np = npb, gv = gb;
        void* kargs[] = {&sv, &dv, &cu, &pk, &rp, &ci, &di, &xv, &w0, &hv,
                         &Nv, &Ev, &nb, &np, &gv};
        hipError_t ce = hipLaunchCooperativeKernel((const void*)coop_k, dim3(coopG),
                                                   dim3(256), kargs, 0, stream);
        coop_done = (ce == hipSuccess);
    }
    if (!coop_done) {
        partition_k<<<npb, 256, 0, stream>>>(src, dst, cursor, pk_arr, E, nbuk);
        csrgemm_k<<<nbuk + gb, 256, 0, stream>>>(pk_arr, cursor, row_ptr, col_idx,
                                                 dinv, x, W0, hs, N, E, nbuk);
    }

    // h1' = fp16( dinv * relu(dinv * agg_w(hs) + b0) )
    agg0_k<<<aggB, 256, 0, stream>>>(hs, row_ptr, col_idx, dinv, b0, h1, N);
    // hs = fp16( h1' @ W1 )   (input pre-scaled -> rows auto-scaled)
    gemm_k<__half, __half, false, false><<<gb, 256, 0, stream>>>(h1, W1, nullptr, hs, N);
    // out_h = dinv * agg(hs) + b1  (fp32)
    agg1_k<<<aggB, 256, 0, stream>>>(hs, row_ptr, col_idx, dinv, b1, out_h, N);
    // heads: one pass over out_h, both weight matrices
    heads_k<<<gb, 256, 0, stream>>>(out_h, Wv, bv, Wt, bt, out_v, out_t, N);
}

// Round 4
// 239.837 us; speedup vs baseline: 1.2437x; 1.2437x over previous
//
#include <hip/hip_runtime.h>
#include <hip/hip_fp16.h>
#include <math.h>

// ---------------------------------------------------------------------------
// GCN 2-layer + two heads, fp32 in/out, MI355X.
//   R9: R7 structure (prep'd W fragments + float4 LDS staging, separate
//   dispatches) + slab partition (no histogram pass) + split-f16 MFMA
//   (cheaper A conversion; gemm1 input exact in f16 -> 2-term, no convert)
//   + single-X-pass heads. Dispatches: memset, prep|partition, csr|gemm0,
//   agg0, gemm1, agg1, heads.
// ---------------------------------------------------------------------------

#define DFEAT 128
#define BSH 8            // bucket = dst >> 8 (256 nodes/bucket)
#define BKE 4096         // edges per partition block
#define SLABCAP 4608     // bucket slab capacity: mean 4096 + 8 sigma

using half8   = __attribute__((ext_vector_type(8))) _Float16;
using floatx4 = __attribute__((ext_vector_type(4))) float;

__device__ __forceinline__ void split_f16(float x, _Float16& hi, _Float16& lo) {
    _Float16 h = (_Float16)x;
    hi = h;
    lo = (_Float16)(x - (float)h);
}

// ---------------- K1: W pre-split to f16 frags  +  slab partition -----------
// blocks [0,256): prep of 4 weight matrices into MFMA hi/lo f16 fragments.
// blocks [256, 256+npb): partition edges into fixed-capacity bucket slabs.
__global__ __launch_bounds__(256) void prep_part_k(const int* __restrict__ src,
                                                   const int* __restrict__ dst,
                                                   int* __restrict__ cursor,
                                                   unsigned* __restrict__ pk_out,
                                                   const float* __restrict__ W0,
                                                   const float* __restrict__ W1,
                                                   const float* __restrict__ W2,
                                                   const float* __restrict__ W3,
                                                   _Float16* __restrict__ hi_all,
                                                   _Float16* __restrict__ lo_all,
                                                   int E, int nbuk) {
    int tid = threadIdx.x;
    if (blockIdx.x < 256) {
        int pb = blockIdx.x;
        int b = pb >> 6;
        const float* W = (b == 0) ? W0 : (b == 1) ? W1 : (b == 2) ? W2 : W3;
        _Float16* hi = hi_all + (size_t)b * 16384;
        _Float16* lo = lo_all + (size_t)b * 16384;
        int i = (pb & 63) * 256 + tid;
        int j = i & 7;
        int lane = (i >> 3) & 63;
        int ts = i >> 9;
        int s = ts & 3, t = ts >> 2;
        int k = s * 32 + (lane >> 4) * 8 + j;
        int n = t * 16 + (lane & 15);
        split_f16(W[k * 128 + n], hi[i], lo[i]);
        return;
    }

    // ---- partition body ----
    __shared__ int h[256];
    __shared__ int base[256];
    h[tid] = 0;
    __syncthreads();
    int B = blockIdx.x - 256;
    int e0 = B * BKE;

    unsigned pk[16];
    unsigned short rk[16];
    unsigned char bk[16];
    int m = 0;
#pragma unroll
    for (int it = 0; it < 4; ++it) {
        int e = e0 + it * 1024 + tid * 4;
        if (e + 3 < E) {
            int4 d4 = *(const int4*)(dst + e);
            int4 s4 = *(const int4*)(src + e);
            int dd[4] = {d4.x, d4.y, d4.z, d4.w};
            int ss[4] = {s4.x, s4.y, s4.z, s4.w};
#pragma unroll
            for (int k = 0; k < 4; ++k) {
                int b = dd[k] >> BSH;
                pk[m] = ((unsigned)dd[k] << 16) | (unsigned)ss[k];
                rk[m] = (unsigned short)atomicAdd(&h[b], 1);
                bk[m] = (unsigned char)b;
                ++m;
            }
        } else {
            for (int k = 0; k < 4; ++k) {
                if (e + k < E) {
                    int d = dst[e + k], sv = src[e + k];
                    int b = d >> BSH;
                    pk[m] = ((unsigned)d << 16) | (unsigned)sv;
                    rk[m] = (unsigned short)atomicAdd(&h[b], 1);
                    bk[m] = (unsigned char)b;
                    ++m;
                }
            }
        }
    }
    __syncthreads();
    if (tid < nbuk && h[tid]) base[tid] = tid * SLABCAP + atomicAdd(&cursor[tid], h[tid]);
    __syncthreads();
    for (int j2 = 0; j2 < m; ++j2)
        pk_out[base[bk[j2]] + (int)rk[j2]] = pk[j2];
}

// ---------------- CSR build from slabs (counts live in cursor) --------------
__device__ __forceinline__ void csr_body(const unsigned* __restrict__ pk_arr,
                                         const int* __restrict__ cursor,
                                         int* __restrict__ row_ptr,
                                         unsigned short* __restrict__ col_idx,
                                         float* __restrict__ dinv,
                                         int N, int E, int nbuk, int b) {
    __shared__ int hcnt[256];
    __shared__ int esc[256];
    __shared__ int sx[256];
    int tid = threadIdx.x;

    int v = (tid < nbuk) ? cursor[tid] : 0;
    sx[tid] = v;
    __syncthreads();
    int x = v;
    for (int o = 1; o < 256; o <<= 1) {
        int y = (tid >= o) ? sx[tid - o] : 0;
        __syncthreads();
        x += y;
        sx[tid] = x;
        __syncthreads();
    }
    int s0 = (b > 0) ? sx[b - 1] : 0;
    int cnt = sx[b] - s0;
    __syncthreads();

    hcnt[tid] = 0;
    __syncthreads();

    const unsigned* slab = pk_arr + (size_t)b * SLABCAP;
    unsigned p[20];
    unsigned short r[20];
    int m = 0;
    for (int i = tid; i < cnt; i += 256) {
        unsigned pp = slab[i];
        int d = (pp >> 16) & 255;
        r[m] = (unsigned short)atomicAdd(&hcnt[d], 1);
        p[m] = pp;
        ++m;
    }
    __syncthreads();

    int hv = hcnt[tid];
    esc[tid] = hv;
    __syncthreads();
    int hx = hv;
    for (int o = 1; o < 256; o <<= 1) {
        int y = (tid >= o) ? esc[tid - o] : 0;
        __syncthreads();
        hx += y;
        esc[tid] = hx;
        __syncthreads();
    }
    int excl = hx - hv;
    __syncthreads();
    esc[tid] = excl;
    __syncthreads();

    int node = (b << BSH) + tid;
    if (node < N) {
        row_ptr[node] = s0 + excl;
        dinv[node] = rsqrtf((float)(hv + 1));   // +1 self loop
    }
    if (node == N) row_ptr[N] = E;

    for (int j = 0; j < m; ++j) {
        int d = (p[j] >> 16) & 255;
        col_idx[s0 + esc[d] + (int)r[j]] = (unsigned short)(p[j] & 0xFFFFu);
    }
}

// ---------------- GEMM pieces (split-f16 MFMA, prepped fragments) -----------
__device__ __forceinline__ void stage_frags(const _Float16* __restrict__ Whi,
                                            const _Float16* __restrict__ Wlo,
                                            _Float16* __restrict__ WhiS,
                                            _Float16* __restrict__ WloS) {
    const int tid = threadIdx.x;
#pragma unroll
    for (int j = 0; j < 8; ++j)
        ((float4*)WhiS)[tid + j * 256] = ((const float4*)Whi)[tid + j * 256];
#pragma unroll
    for (int j = 0; j < 8; ++j)
        ((float4*)WloS)[tid + j * 256] = ((const float4*)Wlo)[tid + j * 256];
}

// A-fragment load. fp32 input: split into f16 hi/lo. fp16 input: exact, hi only.
template <typename InT>
__device__ __forceinline__ void load_A(const InT* __restrict__ X, int M, int m0,
                                       half8 (&Ahi)[2][4], half8 (&Alo)[2][4]) {
    const int lane = threadIdx.x & 63;
    const int quad = lane >> 4, l16 = lane & 15;
#pragma unroll
    for (int r = 0; r < 2; ++r) {
        int row = m0 + r * 16 + l16;
        row = row < M ? row : (M - 1);
        const InT* xr = X + (size_t)row * 128 + quad * 8;
#pragma unroll
        for (int s = 0; s < 4; ++s) {
            if constexpr (sizeof(InT) == 2) {
                Ahi[r][s] = *(const half8*)(xr + s * 32);   // exact
            } else {
                float4 a = ((const float4*)(xr + s * 32))[0];
                float4 b = ((const float4*)(xr + s * 32))[1];
                float v[8] = {a.x, a.y, a.z, a.w, b.x, b.y, b.z, b.w};
#pragma unroll
                for (int j = 0; j < 8; ++j) {
                    _Float16 hi, lo;
                    split_f16(v[j], hi, lo);
                    Ahi[r][s][j] = hi;
                    Alo[r][s][j] = lo;
                }
            }
        }
    }
}

template <typename OutT, int TERMS, bool BIAS, bool RELU>
__device__ __forceinline__ void mfma_store(half8 (&Ahi)[2][4], half8 (&Alo)[2][4],
                                           const _Float16* __restrict__ WhiS,
                                           const _Float16* __restrict__ WloS,
                                           const float* __restrict__ bias,
                                           OutT* __restrict__ Y, int M, int m0) {
    const int lane = threadIdx.x & 63;
    const int quad = lane >> 4, l16 = lane & 15;

    floatx4 acc[2][8];
#pragma unroll
    for (int r = 0; r < 2; ++r)
#pragma unroll
        for (int t = 0; t < 8; ++t) acc[r][t] = (floatx4){0.f, 0.f, 0.f, 0.f};

    const half8* WH = (const half8*)WhiS;
    const half8* WL = (const half8*)WloS;
#pragma unroll
    for (int s = 0; s < 4; ++s) {
#pragma unroll
        for (int t = 0; t < 8; ++t) {
            half8 bh = WH[(t * 4 + s) * 64 + lane];
            half8 bl = WL[(t * 4 + s) * 64 + lane];
#pragma unroll
            for (int r = 0; r < 2; ++r) {
                acc[r][t] = __builtin_amdgcn_mfma_f32_16x16x32_f16(Ahi[r][s], bh, acc[r][t], 0, 0, 0);
                if constexpr (TERMS == 3)
                    acc[r][t] = __builtin_amdgcn_mfma_f32_16x16x32_f16(Alo[r][s], bh, acc[r][t], 0, 0, 0);
                acc[r][t] = __builtin_amdgcn_mfma_f32_16x16x32_f16(Ahi[r][s], bl, acc[r][t], 0, 0, 0);
            }
        }
    }

    float bcol[8];
    if (BIAS) {
#pragma unroll
        for (int t = 0; t < 8; ++t) bcol[t] = bias[t * 16 + l16];
    }
#pragma unroll
    for (int r = 0; r < 2; ++r) {
#pragma unroll
        for (int e = 0; e < 4; ++e) {
            int row = m0 + r * 16 + quad * 4 + e;
            if (row < M) {
                OutT* yr = Y + (size_t)row * 128 + l16;
#pragma unroll
                for (int t = 0; t < 8; ++t) {
                    float v = acc[r][t][e];
                    if (BIAS) v += bcol[t];
                    if (RELU) v = fmaxf(v, 0.f);
                    if constexpr (sizeof(OutT) == 4) yr[t * 16] = v;
                    else yr[t * 16] = __float2half(v);
                }
            }
        }
    }
}

template <typename InT, typename OutT, int TERMS, bool BIAS, bool RELU>
__device__ __forceinline__ void gemm_core(const InT* __restrict__ X,
                                          const _Float16* __restrict__ Whi,
                                          const _Float16* __restrict__ Wlo,
                                          const float* __restrict__ bias,
                                          OutT* __restrict__ Y, int M, int blk,
                                          _Float16* WhiS, _Float16* WloS) {
    stage_frags(Whi, Wlo, WhiS, WloS);
    short8_padding_guard: ;
    half8 Ahi[2][4], Alo[2][4];
    int m0 = blk * 128 + ((threadIdx.x >> 6) << 5);
    load_A<InT>(X, M, m0, Ahi, Alo);
    __syncthreads();
    mfma_store<OutT, TERMS, BIAS, RELU>(Ahi, Alo, WhiS, WloS, bias, Y, M, m0);
}

// ---------------- K2: fused CSR build + layer-0 GEMM ------------------------
__global__ __launch_bounds__(256) void csrgemm_k(const unsigned* __restrict__ pk_arr,
                                                 const int* __restrict__ cursor,
                                                 int* __restrict__ row_ptr,
                                                 unsigned short* __restrict__ col_idx,
                                                 float* __restrict__ dinv,
                                                 const float* __restrict__ X,
                                                 const _Float16* __restrict__ Whi,
                                                 const _Float16* __restrict__ Wlo,
                                                 __half* __restrict__ hs,
                                                 int N, int E, int nbuk) {
    if ((int)blockIdx.x < nbuk) {
        csr_body(pk_arr, cursor, row_ptr, col_idx, dinv, N, E, nbuk, blockIdx.x);
        return;
    }
    __shared__ _Float16 WhiS[16384];
    __shared__ _Float16 WloS[16384];
    gemm_core<float, __half, 3, false, false>(X, Whi, Wlo, nullptr, hs, N,
                                              blockIdx.x - nbuk, WhiS, WloS);
}

// ---------------- standalone GEMM (layer 1: fp16 in, 2 terms) ---------------
template <typename InT, typename OutT, int TERMS, bool BIAS, bool RELU>
__global__ __launch_bounds__(256) void gemm_k(const InT* __restrict__ X,
                                              const _Float16* __restrict__ Whi,
                                              const _Float16* __restrict__ Wlo,
                                              const float* __restrict__ bias,
                                              OutT* __restrict__ Y, int M) {
    __shared__ _Float16 WhiS[16384];
    __shared__ _Float16 WloS[16384];
    gemm_core<InT, OutT, TERMS, BIAS, RELU>(X, Whi, Wlo, bias, Y, M, blockIdx.x,
                                            WhiS, WloS);
}

// ---------------- heads: both GEMMs, one pass over X ------------------------
__global__ __launch_bounds__(256) void heads_k(const float* __restrict__ X,
                                               const _Float16* __restrict__ WhiV,
                                               const _Float16* __restrict__ WloV,
                                               const _Float16* __restrict__ WhiT,
                                               const _Float16* __restrict__ WloT,
                                               const float* __restrict__ bv,
                                               const float* __restrict__ bt,
                                               float* __restrict__ Yv,
                                               float* __restrict__ Yt, int M) {
    __shared__ _Float16 WhiS[16384];
    __shared__ _Float16 WloS[16384];
    half8 Ahi[2][4], Alo[2][4];
    int m0 = blockIdx.x * 128 + ((threadIdx.x >> 6) << 5);
    stage_frags(WhiV, WloV, WhiS, WloS);
    load_A<float>(X, M, m0, Ahi, Alo);
    __syncthreads();
    mfma_store<float, 3, true, true>(Ahi, Alo, WhiS, WloS, bv, Yv, M, m0);
    __syncthreads();                 // all reads of Wv frags done
    stage_frags(WhiT, WloT, WhiS, WloS);
    __syncthreads();
    mfma_store<float, 3, true, true>(Ahi, Alo, WhiS, WloS, bt, Yt, M, m0);
}

// ----------------------------- Aggregates -----------------------------------
// layer 0: h0 table UNSCALED; gathers dinv[col] as edge weight;
// out = dinv_i * relu(dinv_i * acc + b0)  (pre-scaled for layer-1 GEMM).
__global__ __launch_bounds__(256) void agg0_k(const __half* __restrict__ hs,
                                              const int* __restrict__ row_ptr,
                                              const unsigned short* __restrict__ col_idx,
                                              const float* __restrict__ dinv,
                                              const float* __restrict__ bias,
                                              __half* __restrict__ out, int n) {
    const int c = threadIdx.x & 15;
    const int gbase = threadIdx.x & 48;
    int grp = blockIdx.x * 16 + (threadIdx.x >> 4);
    int ngrp = gridDim.x * 16;

    float4 b0 = ((const float4*)bias)[c * 2];
    float4 b1 = ((const float4*)bias)[c * 2 + 1];

    for (int i = grp; i < n; i += ngrp) {
        float di = dinv[i];
        float acc[8];
        {
            uint4 raw = ((const uint4*)(hs + (size_t)i * DFEAT))[c];
            const __half2* hp = (const __half2*)&raw;
#pragma unroll
            for (int k = 0; k < 4; ++k) {
                float2 f = __half22float2(hp[k]);
                acc[2 * k] = f.x * di; acc[2 * k + 1] = f.y * di;
            }
        }
        int s = row_ptr[i];
        int cnt = row_ptr[i + 1] - s;

        for (int base = 0; base < cnt; base += 16) {
            int t = base + c;
            int idx = (t < cnt) ? (int)col_idx[s + t] : 0;
            float dv = (t < cnt) ? dinv[idx] : 0.f;
            int lim = cnt - base; if (lim > 16) lim = 16;
            uint4 vv[16];
#pragma unroll
            for (int q = 0; q < 16; ++q) {
                int ia = __shfl(idx, gbase + q);
                if (q < lim)
                    vv[q] = ((const uint4*)(hs + (size_t)ia * DFEAT))[c];
            }
            float w[16];
#pragma unroll
            for (int q = 0; q < 16; ++q) w[q] = __shfl(dv, gbase + q);
#pragma unroll
            for (int q = 0; q < 16; ++q) {
                if (q < lim) {
                    const __half2* pq = (const __half2*)&vv[q];
#pragma unroll
                    for (int k = 0; k < 4; ++k) {
                        float2 f = __half22float2(pq[k]);
                        acc[2 * k]     = fmaf(f.x, w[q], acc[2 * k]);
                        acc[2 * k + 1] = fmaf(f.y, w[q], acc[2 * k + 1]);
                    }
                }
            }
        }

        float o[8];
        o[0] = fmaf(acc[0], di, b0.x); o[1] = fmaf(acc[1], di, b0.y);
        o[2] = fmaf(acc[2], di, b0.z); o[3] = fmaf(acc[3], di, b0.w);
        o[4] = fmaf(acc[4], di, b1.x); o[5] = fmaf(acc[5], di, b1.y);
        o[6] = fmaf(acc[6], di, b1.z); o[7] = fmaf(acc[7], di, b1.w);
#pragma unroll
        for (int k = 0; k < 8; ++k) o[k] = fmaxf(o[k], 0.f) * di;  // h1' = di*relu

        __half2 hpk[4];
#pragma unroll
        for (int k = 0; k < 4; ++k)
            hpk[k] = __floats2half2_rn(o[2 * k], o[2 * k + 1]);
        ((uint4*)((__half*)out + (size_t)i * DFEAT))[c] = *(uint4*)hpk;
    }
}

// layer 1: table pre-scaled -> unweighted gather; out = dinv_i*acc + b1 (fp32)
__global__ __launch_bounds__(256) void agg1_k(const __half* __restrict__ hs,
                                              const int* __restrict__ row_ptr,
                                              const unsigned short* __restrict__ col_idx,
                                              const float* __restrict__ dinv,
                                              const float* __restrict__ bias,
                                              float* __restrict__ out, int n) {
    const int c = threadIdx.x & 15;
    const int gbase = threadIdx.x & 48;
    int grp = blockIdx.x * 16 + (threadIdx.x >> 4);
    int ngrp = gridDim.x * 16;

    float4 b0 = ((const float4*)bias)[c * 2];
    float4 b1 = ((const float4*)bias)[c * 2 + 1];

    for (int i = grp; i < n; i += ngrp) {
        float acc[8];
        {
            uint4 raw = ((const uint4*)(hs + (size_t)i * DFEAT))[c];
            const __half2* hp = (const __half2*)&raw;
#pragma unroll
            for (int k = 0; k < 4; ++k) {
                float2 f = __half22float2(hp[k]);
                acc[2 * k] = f.x; acc[2 * k + 1] = f.y;
            }
        }
        int s = row_ptr[i];
        int cnt = row_ptr[i + 1] - s;

        for (int base = 0; base < cnt; base += 16) {
            int t = base + c;
            int idx = (t < cnt) ? (int)col_idx[s + t] : 0;
            int lim = cnt - base; if (lim > 16) lim = 16;
            uint4 vv[16];
#pragma unroll
            for (int q = 0; q < 16; ++q) {
                int ia = __shfl(idx, gbase + q);
                if (q < lim)
                    vv[q] = ((const uint4*)(hs + (size_t)ia * DFEAT))[c];
            }
#pragma unroll
            for (int q = 0; q < 16; ++q) {
                if (q < lim) {
                    const __half2* pq = (const __half2*)&vv[q];
#pragma unroll
                    for (int k = 0; k < 4; ++k) {
                        float2 f = __half22float2(pq[k]);
                        acc[2 * k]     += f.x;
                        acc[2 * k + 1] += f.y;
                    }
                }
            }
        }

        float di = dinv[i];
        float o[8];
        o[0] = fmaf(acc[0], di, b0.x); o[1] = fmaf(acc[1], di, b0.y);
        o[2] = fmaf(acc[2], di, b0.z); o[3] = fmaf(acc[3], di, b0.w);
        o[4] = fmaf(acc[4], di, b1.x); o[5] = fmaf(acc[5], di, b1.y);
        o[6] = fmaf(acc[6], di, b1.z); o[7] = fmaf(acc[7], di, b1.w);
        ((float4*)(out + (size_t)i * DFEAT))[c * 2] =
            make_float4(o[0], o[1], o[2], o[3]);
        ((float4*)(out + (size_t)i * DFEAT))[c * 2 + 1] =
            make_float4(o[4], o[5], o[6], o[7]);
    }
}

// ---------------------------------------------------------------------------

static inline size_t align_up(size_t x, size_t a) { return (x + a - 1) & ~(a - 1); }

extern "C" void kernel_launch(void* const* d_in, const int* in_sizes, int n_in,
                              void* d_out, int out_size, void* d_ws, size_t ws_size,
                              hipStream_t stream) {
    const float* x  = (const float*)d_in[0];
    const int*   ei = (const int*)d_in[1];
    const float* W0 = (const float*)d_in[2];
    const float* b0 = (const float*)d_in[3];
    const float* W1 = (const float*)d_in[4];
    const float* b1 = (const float*)d_in[5];
    const float* Wv = (const float*)d_in[6];
    const float* bv = (const float*)d_in[7];
    const float* Wt = (const float*)d_in[8];
    const float* bt = (const float*)d_in[9];

    const int N = in_sizes[0] / DFEAT;
    const int E = in_sizes[1] / 2;
    const int* src = ei;
    const int* dst = ei + E;
    const int nbuk = (N + 255) >> BSH;
    const int npb  = (E + BKE - 1) / BKE;
    const int gb   = (N + 127) / 128;
    const int aggB = (N + 15) / 16;

    // workspace carve-up
    char* w = (char*)d_ws;
    int* cursor      = (int*)w; w += align_up((size_t)256 * 4, 256);
    unsigned* pk_arr = (unsigned*)w; w += align_up((size_t)nbuk * SLABCAP * 4, 256);
    int* row_ptr     = (int*)w; w += align_up((size_t)(N + 1) * 4, 256);
    unsigned short* col_idx = (unsigned short*)w; w += align_up((size_t)E * 2, 256);
    float* dinv      = (float*)w; w += align_up((size_t)N * 4, 256);
    _Float16* whi_all = (_Float16*)w; w += align_up(4 * 16384 * 2, 256);
    _Float16* wlo_all = (_Float16*)w; w += align_up(4 * 16384 * 2, 256);
    __half* hs       = (__half*)w; w += align_up((size_t)N * DFEAT * 2, 256);
    __half* h1       = (__half*)w; w += align_up((size_t)N * DFEAT * 2, 256);

    _Float16* w0hi = whi_all;            _Float16* w0lo = wlo_all;
    _Float16* w1hi = whi_all + 16384;    _Float16* w1lo = wlo_all + 16384;
    _Float16* wvhi = whi_all + 2*16384;  _Float16* wvlo = wlo_all + 2*16384;
    _Float16* wthi = whi_all + 3*16384;  _Float16* wtlo = wlo_all + 3*16384;

    float* out_h = (float*)d_out;
    float* out_v = out_h + (size_t)N * DFEAT;
    float* out_t = out_h + 2 * (size_t)N * DFEAT;

    hipMemsetAsync(cursor, 0, 256 * 4, stream);

    // K1: W prep + slab partition (one dispatch)
    prep_part_k<<<256 + npb, 256, 0, stream>>>(src, dst, cursor, pk_arr,
                                               W0, W1, Wv, Wt, whi_all, wlo_all,
                                               E, nbuk);
    // K2: CSR build + unscaled layer-0 GEMM (co-resident)
    csrgemm_k<<<nbuk + gb, 256, 0, stream>>>(pk_arr, cursor, row_ptr, col_idx,
                                             dinv, x, w0hi, w0lo, hs, N, E, nbuk);
    // K3: weighted aggregate -> h1' = fp16( dinv*relu(dinv*acc + b0) )
    agg0_k<<<aggB, 256, 0, stream>>>(hs, row_ptr, col_idx, dinv, b0, h1, N);
    // K4: layer-1 GEMM, fp16 input exact -> 2-term, no A conversion
    gemm_k<__half, __half, 2, false, false><<<gb, 256, 0, stream>>>(h1, w1hi, w1lo,
                                                                    nullptr, hs, N);
    // K5: plain aggregate -> out_h = dinv*acc + b1 (fp32)
    agg1_k<<<aggB, 256, 0, stream>>>(hs, row_ptr, col_idx, dinv, b1, out_h, N);
    // K6: heads, single pass over out_h
    heads_k<<<gb, 256, 0, stream>>>(out_h, wvhi, wvlo, wthi, wtlo, bv, bt,
                                    out_v, out_t, N);
}

// Round 5
// 239.680 us; speedup vs baseline: 1.2445x; 1.0007x over previous
//
#include <hip/hip_runtime.h>
#include <hip/hip_fp16.h>
#include <math.h>

// ---------------------------------------------------------------------------
// GCN 2-layer + two heads, fp32 in/out, MI355X.
//   R10: 5 dispatches. R9 base (split-f16 MFMA, slab partition, prepped W
//   fragments) + two new fusions exploiting "16-node agg block == 16-row
//   MFMA tile":
//     agg0gemm1_k: weighted agg -> LDS transpose (padded, 2-way) -> 2-term
//                  f16 GEMM with B-fragments streamed from L2 (no big LDS,
//                  no h1' round trip).
//     agg1heads_k: plain agg -> write out_h -> LDS fp32 tile -> both head
//                  GEMMs (3-term split), B streamed from L2.
//   Dispatches: memset, prep_part, csrgemm, agg0gemm1, agg1heads.
// ---------------------------------------------------------------------------

#define DFEAT 128
#define BSH 8            // bucket = dst >> 8 (256 nodes/bucket)
#define BKE 4096         // edges per partition block
#define SLABCAP 4608     // bucket slab capacity: mean 4096 + 8 sigma

using half8   = __attribute__((ext_vector_type(8))) _Float16;
using floatx4 = __attribute__((ext_vector_type(4))) float;

__device__ __forceinline__ void split_f16(float x, _Float16& hi, _Float16& lo) {
    _Float16 h = (_Float16)x;
    hi = h;
    lo = (_Float16)(x - (float)h);
}

// ---------------- K1: W pre-split to f16 frags  +  slab partition -----------
__global__ __launch_bounds__(256) void prep_part_k(const int* __restrict__ src,
                                                   const int* __restrict__ dst,
                                                   int* __restrict__ cursor,
                                                   unsigned* __restrict__ pk_out,
                                                   const float* __restrict__ W0,
                                                   const float* __restrict__ W1,
                                                   const float* __restrict__ W2,
                                                   const float* __restrict__ W3,
                                                   _Float16* __restrict__ hi_all,
                                                   _Float16* __restrict__ lo_all,
                                                   int E, int nbuk) {
    int tid = threadIdx.x;
    if (blockIdx.x < 256) {
        int pb = blockIdx.x;
        int b = pb >> 6;
        const float* W = (b == 0) ? W0 : (b == 1) ? W1 : (b == 2) ? W2 : W3;
        _Float16* hi = hi_all + (size_t)b * 16384;
        _Float16* lo = lo_all + (size_t)b * 16384;
        int i = (pb & 63) * 256 + tid;
        int j = i & 7;
        int lane = (i >> 3) & 63;
        int ts = i >> 9;
        int s = ts & 3, t = ts >> 2;
        int k = s * 32 + (lane >> 4) * 8 + j;
        int n = t * 16 + (lane & 15);
        split_f16(W[k * 128 + n], hi[i], lo[i]);
        return;
    }

    // ---- partition body ----
    __shared__ int h[256];
    __shared__ int base[256];
    h[tid] = 0;
    __syncthreads();
    int B = blockIdx.x - 256;
    int e0 = B * BKE;

    unsigned pk[16];
    unsigned short rk[16];
    unsigned char bk[16];
    int m = 0;
#pragma unroll
    for (int it = 0; it < 4; ++it) {
        int e = e0 + it * 1024 + tid * 4;
        if (e + 3 < E) {
            int4 d4 = *(const int4*)(dst + e);
            int4 s4 = *(const int4*)(src + e);
            int dd[4] = {d4.x, d4.y, d4.z, d4.w};
            int ss[4] = {s4.x, s4.y, s4.z, s4.w};
#pragma unroll
            for (int k = 0; k < 4; ++k) {
                int b = dd[k] >> BSH;
                pk[m] = ((unsigned)dd[k] << 16) | (unsigned)ss[k];
                rk[m] = (unsigned short)atomicAdd(&h[b], 1);
                bk[m] = (unsigned char)b;
                ++m;
            }
        } else {
            for (int k = 0; k < 4; ++k) {
                if (e + k < E) {
                    int d = dst[e + k], sv = src[e + k];
                    int b = d >> BSH;
                    pk[m] = ((unsigned)d << 16) | (unsigned)sv;
                    rk[m] = (unsigned short)atomicAdd(&h[b], 1);
                    bk[m] = (unsigned char)b;
                    ++m;
                }
            }
        }
    }
    __syncthreads();
    if (tid < nbuk && h[tid]) base[tid] = tid * SLABCAP + atomicAdd(&cursor[tid], h[tid]);
    __syncthreads();
    for (int j2 = 0; j2 < m; ++j2)
        pk_out[base[bk[j2]] + (int)rk[j2]] = pk[j2];
}

// ---------------- CSR build from slabs (counts live in cursor) --------------
__device__ __forceinline__ void csr_body(const unsigned* __restrict__ pk_arr,
                                         const int* __restrict__ cursor,
                                         int* __restrict__ row_ptr,
                                         unsigned short* __restrict__ col_idx,
                                         float* __restrict__ dinv,
                                         int N, int E, int nbuk, int b) {
    __shared__ int hcnt[256];
    __shared__ int esc[256];
    __shared__ int sx[256];
    int tid = threadIdx.x;

    int v = (tid < nbuk) ? cursor[tid] : 0;
    sx[tid] = v;
    __syncthreads();
    int x = v;
    for (int o = 1; o < 256; o <<= 1) {
        int y = (tid >= o) ? sx[tid - o] : 0;
        __syncthreads();
        x += y;
        sx[tid] = x;
        __syncthreads();
    }
    int s0 = (b > 0) ? sx[b - 1] : 0;
    int cnt = sx[b] - s0;
    __syncthreads();

    hcnt[tid] = 0;
    __syncthreads();

    const unsigned* slab = pk_arr + (size_t)b * SLABCAP;
    unsigned p[20];
    unsigned short r[20];
    int m = 0;
    for (int i = tid; i < cnt; i += 256) {
        unsigned pp = slab[i];
        int d = (pp >> 16) & 255;
        r[m] = (unsigned short)atomicAdd(&hcnt[d], 1);
        p[m] = pp;
        ++m;
    }
    __syncthreads();

    int hv = hcnt[tid];
    esc[tid] = hv;
    __syncthreads();
    int hx = hv;
    for (int o = 1; o < 256; o <<= 1) {
        int y = (tid >= o) ? esc[tid - o] : 0;
        __syncthreads();
        hx += y;
        esc[tid] = hx;
        __syncthreads();
    }
    int excl = hx - hv;
    __syncthreads();
    esc[tid] = excl;
    __syncthreads();

    int node = (b << BSH) + tid;
    if (node < N) {
        row_ptr[node] = s0 + excl;
        dinv[node] = rsqrtf((float)(hv + 1));   // +1 self loop
    }
    if (node == N) row_ptr[N] = E;

    for (int j = 0; j < m; ++j) {
        int d = (p[j] >> 16) & 255;
        col_idx[s0 + esc[d] + (int)r[j]] = (unsigned short)(p[j] & 0xFFFFu);
    }
}

// ---------------- GEMM pieces (split-f16 MFMA, prepped fragments) -----------
__device__ __forceinline__ void stage_frags(const _Float16* __restrict__ Whi,
                                            const _Float16* __restrict__ Wlo,
                                            _Float16* __restrict__ WhiS,
                                            _Float16* __restrict__ WloS) {
    const int tid = threadIdx.x;
#pragma unroll
    for (int j = 0; j < 8; ++j)
        ((float4*)WhiS)[tid + j * 256] = ((const float4*)Whi)[tid + j * 256];
#pragma unroll
    for (int j = 0; j < 8; ++j)
        ((float4*)WloS)[tid + j * 256] = ((const float4*)Wlo)[tid + j * 256];
}

template <typename InT>
__device__ __forceinline__ void load_A(const InT* __restrict__ X, int M, int m0,
                                       half8 (&Ahi)[2][4], half8 (&Alo)[2][4]) {
    const int lane = threadIdx.x & 63;
    const int quad = lane >> 4, l16 = lane & 15;
#pragma unroll
    for (int r = 0; r < 2; ++r) {
        int row = m0 + r * 16 + l16;
        row = row < M ? row : (M - 1);
        const InT* xr = X + (size_t)row * 128 + quad * 8;
#pragma unroll
        for (int s = 0; s < 4; ++s) {
            if constexpr (sizeof(InT) == 2) {
                Ahi[r][s] = *(const half8*)(xr + s * 32);   // exact
            } else {
                float4 a = ((const float4*)(xr + s * 32))[0];
                float4 b = ((const float4*)(xr + s * 32))[1];
                float v[8] = {a.x, a.y, a.z, a.w, b.x, b.y, b.z, b.w};
#pragma unroll
                for (int j = 0; j < 8; ++j) {
                    _Float16 hi, lo;
                    split_f16(v[j], hi, lo);
                    Ahi[r][s][j] = hi;
                    Alo[r][s][j] = lo;
                }
            }
        }
    }
}

template <typename OutT, int TERMS, bool BIAS, bool RELU>
__device__ __forceinline__ void mfma_store(half8 (&Ahi)[2][4], half8 (&Alo)[2][4],
                                           const _Float16* __restrict__ WhiS,
                                           const _Float16* __restrict__ WloS,
                                           const float* __restrict__ bias,
                                           OutT* __restrict__ Y, int M, int m0) {
    const int lane = threadIdx.x & 63;
    const int quad = lane >> 4, l16 = lane & 15;

    floatx4 acc[2][8];
#pragma unroll
    for (int r = 0; r < 2; ++r)
#pragma unroll
        for (int t = 0; t < 8; ++t) acc[r][t] = (floatx4){0.f, 0.f, 0.f, 0.f};

    const half8* WH = (const half8*)WhiS;
    const half8* WL = (const half8*)WloS;
#pragma unroll
    for (int s = 0; s < 4; ++s) {
#pragma unroll
        for (int t = 0; t < 8; ++t) {
            half8 bh = WH[(t * 4 + s) * 64 + lane];
            half8 bl = WL[(t * 4 + s) * 64 + lane];
#pragma unroll
            for (int r = 0; r < 2; ++r) {
                acc[r][t] = __builtin_amdgcn_mfma_f32_16x16x32_f16(Ahi[r][s], bh, acc[r][t], 0, 0, 0);
                if constexpr (TERMS == 3)
                    acc[r][t] = __builtin_amdgcn_mfma_f32_16x16x32_f16(Alo[r][s], bh, acc[r][t], 0, 0, 0);
                acc[r][t] = __builtin_amdgcn_mfma_f32_16x16x32_f16(Ahi[r][s], bl, acc[r][t], 0, 0, 0);
            }
        }
    }

    float bcol[8];
    if (BIAS) {
#pragma unroll
        for (int t = 0; t < 8; ++t) bcol[t] = bias[t * 16 + l16];
    }
#pragma unroll
    for (int r = 0; r < 2; ++r) {
#pragma unroll
        for (int e = 0; e < 4; ++e) {
            int row = m0 + r * 16 + quad * 4 + e;
            if (row < M) {
                OutT* yr = Y + (size_t)row * 128 + l16;
#pragma unroll
                for (int t = 0; t < 8; ++t) {
                    float v = acc[r][t][e];
                    if (BIAS) v += bcol[t];
                    if (RELU) v = fmaxf(v, 0.f);
                    if constexpr (sizeof(OutT) == 4) yr[t * 16] = v;
                    else yr[t * 16] = __float2half(v);
                }
            }
        }
    }
}

// ---------------- K2: fused CSR build + layer-0 GEMM ------------------------
__global__ __launch_bounds__(256) void csrgemm_k(const unsigned* __restrict__ pk_arr,
                                                 const int* __restrict__ cursor,
                                                 int* __restrict__ row_ptr,
                                                 unsigned short* __restrict__ col_idx,
                                                 float* __restrict__ dinv,
                                                 const float* __restrict__ X,
                                                 const _Float16* __restrict__ Whi,
                                                 const _Float16* __restrict__ Wlo,
                                                 __half* __restrict__ hs,
                                                 int N, int E, int nbuk) {
    if ((int)blockIdx.x < nbuk) {
        csr_body(pk_arr, cursor, row_ptr, col_idx, dinv, N, E, nbuk, blockIdx.x);
        return;
    }
    __shared__ _Float16 WhiS[16384];
    __shared__ _Float16 WloS[16384];
    stage_frags(Whi, Wlo, WhiS, WloS);
    half8 Ahi[2][4], Alo[2][4];
    int m0 = (blockIdx.x - nbuk) * 128 + ((threadIdx.x >> 6) << 5);
    load_A<float>(X, N, m0, Ahi, Alo);
    __syncthreads();
    mfma_store<__half, 3, false, false>(Ahi, Alo, WhiS, WloS, nullptr, hs, N, m0);
}

// ---------------- K3: fused weighted agg + layer-1 GEMM ---------------------
// Block owns 16 consecutive nodes (one per 16-lane group). Phase 1: weighted
// aggregate (gathers dinv[col]); result rows -> padded LDS f16 tile (no h1'
// global round trip). Phase 2: 16x128 2-term f16 GEMM, B-fragments streamed
// straight from L2-resident prepped W1 arrays. Output: hs (fp16).
#define LP16 136   // f16 elems per LDS row (272B stride -> 2-way banks)
__global__ __launch_bounds__(256) void agg0gemm1_k(const __half* __restrict__ hs,
                                                   const int* __restrict__ row_ptr,
                                                   const unsigned short* __restrict__ col_idx,
                                                   const float* __restrict__ dinv,
                                                   const float* __restrict__ bias,
                                                   const _Float16* __restrict__ W1hi,
                                                   const _Float16* __restrict__ W1lo,
                                                   __half* __restrict__ out_hs, int n) {
    __shared__ _Float16 A[16 * LP16];
    const int tid = threadIdx.x;
    const int c = tid & 15;
    const int g = tid >> 4;
    const int gbase = tid & 48;

    int i = blockIdx.x * 16 + g;

    if (i < n) {
        float4 b0 = ((const float4*)bias)[c * 2];
        float4 b1 = ((const float4*)bias)[c * 2 + 1];
        float di = dinv[i];
        float acc[8];
        {
            uint4 raw = ((const uint4*)(hs + (size_t)i * DFEAT))[c];
            const __half2* hp = (const __half2*)&raw;
#pragma unroll
            for (int k = 0; k < 4; ++k) {
                float2 f = __half22float2(hp[k]);
                acc[2 * k] = f.x * di; acc[2 * k + 1] = f.y * di;
            }
        }
        int s = row_ptr[i];
        int cnt = row_ptr[i + 1] - s;

        for (int base = 0; base < cnt; base += 16) {
            int t = base + c;
            int idx = (t < cnt) ? (int)col_idx[s + t] : 0;
            float dv = (t < cnt) ? dinv[idx] : 0.f;
            int lim = cnt - base; if (lim > 16) lim = 16;
            uint4 vv[16];
#pragma unroll
            for (int q = 0; q < 16; ++q) {
                int ia = __shfl(idx, gbase + q);
                if (q < lim)
                    vv[q] = ((const uint4*)(hs + (size_t)ia * DFEAT))[c];
            }
            float w[16];
#pragma unroll
            for (int q = 0; q < 16; ++q) w[q] = __shfl(dv, gbase + q);
#pragma unroll
            for (int q = 0; q < 16; ++q) {
                if (q < lim) {
                    const __half2* pq = (const __half2*)&vv[q];
#pragma unroll
                    for (int k = 0; k < 4; ++k) {
                        float2 f = __half22float2(pq[k]);
                        acc[2 * k]     = fmaf(f.x, w[q], acc[2 * k]);
                        acc[2 * k + 1] = fmaf(f.y, w[q], acc[2 * k + 1]);
                    }
                }
            }
        }

        float o[8];
        o[0] = fmaf(acc[0], di, b0.x); o[1] = fmaf(acc[1], di, b0.y);
        o[2] = fmaf(acc[2], di, b0.z); o[3] = fmaf(acc[3], di, b0.w);
        o[4] = fmaf(acc[4], di, b1.x); o[5] = fmaf(acc[5], di, b1.y);
        o[6] = fmaf(acc[6], di, b1.z); o[7] = fmaf(acc[7], di, b1.w);
        _Float16 hv[8];
#pragma unroll
        for (int k = 0; k < 8; ++k) hv[k] = (_Float16)(fmaxf(o[k], 0.f) * di);
        *(uint4*)(&A[g * LP16 + c * 8]) = *(uint4*)hv;
    } else {
        uint4 z = {0u, 0u, 0u, 0u};
        *(uint4*)(&A[g * LP16 + c * 8]) = z;
    }

    __syncthreads();

    // ---- phase 2: GEMM (each wave: 2 column blocks of 16) ----
    const int lane = tid & 63, wave = tid >> 6;
    const int quad = lane >> 4, l16 = lane & 15;
    half8 a[4];
#pragma unroll
    for (int s = 0; s < 4; ++s)
        a[s] = *(const half8*)(&A[l16 * LP16 + s * 32 + quad * 8]);

    floatx4 acc2[2];
    acc2[0] = (floatx4){0.f, 0.f, 0.f, 0.f};
    acc2[1] = (floatx4){0.f, 0.f, 0.f, 0.f};
#pragma unroll
    for (int s = 0; s < 4; ++s) {
#pragma unroll
        for (int tt = 0; tt < 2; ++tt) {
            int t = wave * 2 + tt;
            half8 bh = *(const half8*)(W1hi + ((size_t)((t * 4 + s) * 64 + lane)) * 8);
            half8 bl = *(const half8*)(W1lo + ((size_t)((t * 4 + s) * 64 + lane)) * 8);
            acc2[tt] = __builtin_amdgcn_mfma_f32_16x16x32_f16(a[s], bh, acc2[tt], 0, 0, 0);
            acc2[tt] = __builtin_amdgcn_mfma_f32_16x16x32_f16(a[s], bl, acc2[tt], 0, 0, 0);
        }
    }
#pragma unroll
    for (int tt = 0; tt < 2; ++tt) {
        int col = (wave * 2 + tt) * 16 + l16;
#pragma unroll
        for (int e = 0; e < 4; ++e) {
            int row = blockIdx.x * 16 + quad * 4 + e;
            if (row < n)
                out_hs[(size_t)row * DFEAT + col] = __float2half(acc2[tt][e]);
        }
    }
}

// ---------------- K4: fused plain agg + heads -------------------------------
// Phase 1: unweighted aggregate (table pre-scaled), write out_h (fp32 output)
// and stash rows in fp32 LDS tile. Phase 2: both head GEMMs (3-term split),
// B streamed from L2.
#define LP32 132   // f32 elems per LDS row (528B stride -> 2-way banks)
__global__ __launch_bounds__(256) void agg1heads_k(const __half* __restrict__ hs,
                                                   const int* __restrict__ row_ptr,
                                                   const unsigned short* __restrict__ col_idx,
                                                   const float* __restrict__ dinv,
                                                   const float* __restrict__ bias,
                                                   const _Float16* __restrict__ WvHi,
                                                   const _Float16* __restrict__ WvLo,
                                                   const _Float16* __restrict__ WtHi,
                                                   const _Float16* __restrict__ WtLo,
                                                   const float* __restrict__ bv,
                                                   const float* __restrict__ bt,
                                                   float* __restrict__ out_h,
                                                   float* __restrict__ out_v,
                                                   float* __restrict__ out_t, int n) {
    __shared__ float Af[16 * LP32];
    const int tid = threadIdx.x;
    const int c = tid & 15;
    const int g = tid >> 4;
    const int gbase = tid & 48;

    int i = blockIdx.x * 16 + g;

    if (i < n) {
        float4 b0 = ((const float4*)bias)[c * 2];
        float4 b1 = ((const float4*)bias)[c * 2 + 1];
        float acc[8];
        {
            uint4 raw = ((const uint4*)(hs + (size_t)i * DFEAT))[c];
            const __half2* hp = (const __half2*)&raw;
#pragma unroll
            for (int k = 0; k < 4; ++k) {
                float2 f = __half22float2(hp[k]);
                acc[2 * k] = f.x; acc[2 * k + 1] = f.y;
            }
        }
        int s = row_ptr[i];
        int cnt = row_ptr[i + 1] - s;

        for (int base = 0; base < cnt; base += 16) {
            int t = base + c;
            int idx = (t < cnt) ? (int)col_idx[s + t] : 0;
            int lim = cnt - base; if (lim > 16) lim = 16;
            uint4 vv[16];
#pragma unroll
            for (int q = 0; q < 16; ++q) {
                int ia = __shfl(idx, gbase + q);
                if (q < lim)
                    vv[q] = ((const uint4*)(hs + (size_t)ia * DFEAT))[c];
            }
#pragma unroll
            for (int q = 0; q < 16; ++q) {
                if (q < lim) {
                    const __half2* pq = (const __half2*)&vv[q];
#pragma unroll
                    for (int k = 0; k < 4; ++k) {
                        float2 f = __half22float2(pq[k]);
                        acc[2 * k]     += f.x;
                        acc[2 * k + 1] += f.y;
                    }
                }
            }
        }

        float di = dinv[i];
        float o[8];
        o[0] = fmaf(acc[0], di, b0.x); o[1] = fmaf(acc[1], di, b0.y);
        o[2] = fmaf(acc[2], di, b0.z); o[3] = fmaf(acc[3], di, b0.w);
        o[4] = fmaf(acc[4], di, b1.x); o[5] = fmaf(acc[5], di, b1.y);
        o[6] = fmaf(acc[6], di, b1.z); o[7] = fmaf(acc[7], di, b1.w);
        float4 w0 = make_float4(o[0], o[1], o[2], o[3]);
        float4 w1 = make_float4(o[4], o[5], o[6], o[7]);
        ((float4*)(out_h + (size_t)i * DFEAT))[c * 2] = w0;
        ((float4*)(out_h + (size_t)i * DFEAT))[c * 2 + 1] = w1;
        *(float4*)(&Af[g * LP32 + c * 8]) = w0;
        *(float4*)(&Af[g * LP32 + c * 8 + 4]) = w1;
    } else {
        float4 z = make_float4(0.f, 0.f, 0.f, 0.f);
        *(float4*)(&Af[g * LP32 + c * 8]) = z;
        *(float4*)(&Af[g * LP32 + c * 8 + 4]) = z;
    }

    __syncthreads();

    // ---- phase 2: both head GEMMs ----
    const int lane = tid & 63, wave = tid >> 6;
    const int quad = lane >> 4, l16 = lane & 15;
    half8 ahi[4], alo[4];
#pragma unroll
    for (int s = 0; s < 4; ++s) {
        float4 fa = *(const float4*)(&Af[l16 * LP32 + s * 32 + quad * 8]);
        float4 fb = *(const float4*)(&Af[l16 * LP32 + s * 32 + quad * 8 + 4]);
        float v[8] = {fa.x, fa.y, fa.z, fa.w, fb.x, fb.y, fb.z, fb.w};
#pragma unroll
        for (int j = 0; j < 8; ++j) {
            _Float16 hi, lo;
            split_f16(v[j], hi, lo);
            ahi[s][j] = hi;
            alo[s][j] = lo;
        }
    }

    floatx4 accV[2], accT[2];
#pragma unroll
    for (int tt = 0; tt < 2; ++tt) {
        accV[tt] = (floatx4){0.f, 0.f, 0.f, 0.f};
        accT[tt] = (floatx4){0.f, 0.f, 0.f, 0.f};
    }
#pragma unroll
    for (int s = 0; s < 4; ++s) {
#pragma unroll
        for (int tt = 0; tt < 2; ++tt) {
            size_t fi = ((size_t)(((wave * 2 + tt) * 4 + s) * 64 + lane)) * 8;
            half8 bhv = *(const half8*)(WvHi + fi);
            half8 blv = *(const half8*)(WvLo + fi);
            accV[tt] = __builtin_amdgcn_mfma_f32_16x16x32_f16(ahi[s], bhv, accV[tt], 0, 0, 0);
            accV[tt] = __builtin_amdgcn_mfma_f32_16x16x32_f16(alo[s], bhv, accV[tt], 0, 0, 0);
            accV[tt] = __builtin_amdgcn_mfma_f32_16x16x32_f16(ahi[s], blv, accV[tt], 0, 0, 0);
            half8 bht = *(const half8*)(WtHi + fi);
            half8 blt = *(const half8*)(WtLo + fi);
            accT[tt] = __builtin_amdgcn_mfma_f32_16x16x32_f16(ahi[s], bht, accT[tt], 0, 0, 0);
            accT[tt] = __builtin_amdgcn_mfma_f32_16x16x32_f16(alo[s], bht, accT[tt], 0, 0, 0);
            accT[tt] = __builtin_amdgcn_mfma_f32_16x16x32_f16(ahi[s], blt, accT[tt], 0, 0, 0);
        }
    }
#pragma unroll
    for (int tt = 0; tt < 2; ++tt) {
        int col = (wave * 2 + tt) * 16 + l16;
        float bcv = bv[col], bct = bt[col];
#pragma unroll
        for (int e = 0; e < 4; ++e) {
            int row = blockIdx.x * 16 + quad * 4 + e;
            if (row < n) {
                out_v[(size_t)row * DFEAT + col] = fmaxf(accV[tt][e] + bcv, 0.f);
                out_t[(size_t)row * DFEAT + col] = fmaxf(accT[tt][e] + bct, 0.f);
            }
        }
    }
}

// ---------------------------------------------------------------------------

static inline size_t align_up(size_t x, size_t a) { return (x + a - 1) & ~(a - 1); }

extern "C" void kernel_launch(void* const* d_in, const int* in_sizes, int n_in,
                              void* d_out, int out_size, void* d_ws, size_t ws_size,
                              hipStream_t stream) {
    const float* x  = (const float*)d_in[0];
    const int*   ei = (const int*)d_in[1];
    const float* W0 = (const float*)d_in[2];
    const float* b0 = (const float*)d_in[3];
    const float* W1 = (const float*)d_in[4];
    const float* b1 = (const float*)d_in[5];
    const float* Wv = (const float*)d_in[6];
    const float* bv = (const float*)d_in[7];
    const float* Wt = (const float*)d_in[8];
    const float* bt = (const float*)d_in[9];

    const int N = in_sizes[0] / DFEAT;
    const int E = in_sizes[1] / 2;
    const int* src = ei;
    const int* dst = ei + E;
    const int nbuk = (N + 255) >> BSH;
    const int npb  = (E + BKE - 1) / BKE;
    const int gb   = (N + 127) / 128;
    const int fusB = (N + 15) / 16;

    // workspace carve-up
    char* w = (char*)d_ws;
    int* cursor      = (int*)w; w += align_up((size_t)256 * 4, 256);
    unsigned* pk_arr = (unsigned*)w; w += align_up((size_t)nbuk * SLABCAP * 4, 256);
    int* row_ptr     = (int*)w; w += align_up((size_t)(N + 1) * 4, 256);
    unsigned short* col_idx = (unsigned short*)w; w += align_up((size_t)E * 2, 256);
    float* dinv      = (float*)w; w += align_up((size_t)N * 4, 256);
    _Float16* whi_all = (_Float16*)w; w += align_up(4 * 16384 * 2, 256);
    _Float16* wlo_all = (_Float16*)w; w += align_up(4 * 16384 * 2, 256);
    __half* hs       = (__half*)w; w += align_up((size_t)N * DFEAT * 2, 256);
    __half* hs2      = (__half*)w; w += align_up((size_t)N * DFEAT * 2, 256);

    _Float16* w0hi = whi_all;            _Float16* w0lo = wlo_all;
    _Float16* w1hi = whi_all + 16384;    _Float16* w1lo = wlo_all + 16384;
    _Float16* wvhi = whi_all + 2*16384;  _Float16* wvlo = wlo_all + 2*16384;
    _Float16* wthi = whi_all + 3*16384;  _Float16* wtlo = wlo_all + 3*16384;

    float* out_h = (float*)d_out;
    float* out_v = out_h + (size_t)N * DFEAT;
    float* out_t = out_h + 2 * (size_t)N * DFEAT;

    hipMemsetAsync(cursor, 0, 256 * 4, stream);

    // K1: W prep + slab partition
    prep_part_k<<<256 + npb, 256, 0, stream>>>(src, dst, cursor, pk_arr,
                                               W0, W1, Wv, Wt, whi_all, wlo_all,
                                               E, nbuk);
    // K2: CSR build + unscaled layer-0 GEMM (co-resident)
    csrgemm_k<<<nbuk + gb, 256, 0, stream>>>(pk_arr, cursor, row_ptr, col_idx,
                                             dinv, x, w0hi, w0lo, hs, N, E, nbuk);
    // K3: weighted agg + layer-1 GEMM fused -> hs2
    agg0gemm1_k<<<fusB, 256, 0, stream>>>(hs, row_ptr, col_idx, dinv, b0,
                                          w1hi, w1lo, hs2, N);
    // K4: plain agg + both heads fused -> out_h, out_v, out_t
    agg1heads_k<<<fusB, 256, 0, stream>>>(hs2, row_ptr, col_idx, dinv, b1,
                                          wvhi, wvlo, wthi, wtlo, bv, bt,
                                          out_h, out_v, out_t, N);
}

// Round 6
// 215.737 us; speedup vs baseline: 1.3826x; 1.1110x over previous
//
#include <hip/hip_runtime.h>
#include <hip/hip_fp16.h>
#include <math.h>

// ---------------------------------------------------------------------------
// GCN 2-layer + two heads, fp32 in/out, MI355X.
//   R11: R10 structure (5 dispatches) + VGPR diet on the two fused agg
//   kernels (the measured hot spots, 77us @ 68 VGPR -> occupancy capped at
//   4 waves/SIMD): 8-deep gather batches, epilogue-loaded bias, consume-time
//   weight shfl, sequential head GEMMs, __launch_bounds__(256,8).
// ---------------------------------------------------------------------------

#define DFEAT 128
#define BSH 8            // bucket = dst >> 8 (256 nodes/bucket)
#define BKE 4096         // edges per partition block
#define SLABCAP 4608     // bucket slab capacity: mean 4096 + 8 sigma

using half8   = __attribute__((ext_vector_type(8))) _Float16;
using floatx4 = __attribute__((ext_vector_type(4))) float;

__device__ __forceinline__ void split_f16(float x, _Float16& hi, _Float16& lo) {
    _Float16 h = (_Float16)x;
    hi = h;
    lo = (_Float16)(x - (float)h);
}

// ---------------- K1: W pre-split to f16 frags  +  slab partition -----------
__global__ __launch_bounds__(256) void prep_part_k(const int* __restrict__ src,
                                                   const int* __restrict__ dst,
                                                   int* __restrict__ cursor,
                                                   unsigned* __restrict__ pk_out,
                                                   const float* __restrict__ W0,
                                                   const float* __restrict__ W1,
                                                   const float* __restrict__ W2,
                                                   const float* __restrict__ W3,
                                                   _Float16* __restrict__ hi_all,
                                                   _Float16* __restrict__ lo_all,
                                                   int E, int nbuk) {
    int tid = threadIdx.x;
    if (blockIdx.x < 256) {
        int pb = blockIdx.x;
        int b = pb >> 6;
        const float* W = (b == 0) ? W0 : (b == 1) ? W1 : (b == 2) ? W2 : W3;
        _Float16* hi = hi_all + (size_t)b * 16384;
        _Float16* lo = lo_all + (size_t)b * 16384;
        int i = (pb & 63) * 256 + tid;
        int j = i & 7;
        int lane = (i >> 3) & 63;
        int ts = i >> 9;
        int s = ts & 3, t = ts >> 2;
        int k = s * 32 + (lane >> 4) * 8 + j;
        int n = t * 16 + (lane & 15);
        split_f16(W[k * 128 + n], hi[i], lo[i]);
        return;
    }

    // ---- partition body ----
    __shared__ int h[256];
    __shared__ int base[256];
    h[tid] = 0;
    __syncthreads();
    int B = blockIdx.x - 256;
    int e0 = B * BKE;

    unsigned pk[16];
    unsigned short rk[16];
    unsigned char bk[16];
    int m = 0;
#pragma unroll
    for (int it = 0; it < 4; ++it) {
        int e = e0 + it * 1024 + tid * 4;
        if (e + 3 < E) {
            int4 d4 = *(const int4*)(dst + e);
            int4 s4 = *(const int4*)(src + e);
            int dd[4] = {d4.x, d4.y, d4.z, d4.w};
            int ss[4] = {s4.x, s4.y, s4.z, s4.w};
#pragma unroll
            for (int k = 0; k < 4; ++k) {
                int b = dd[k] >> BSH;
                pk[m] = ((unsigned)dd[k] << 16) | (unsigned)ss[k];
                rk[m] = (unsigned short)atomicAdd(&h[b], 1);
                bk[m] = (unsigned char)b;
                ++m;
            }
        } else {
            for (int k = 0; k < 4; ++k) {
                if (e + k < E) {
                    int d = dst[e + k], sv = src[e + k];
                    int b = d >> BSH;
                    pk[m] = ((unsigned)d << 16) | (unsigned)sv;
                    rk[m] = (unsigned short)atomicAdd(&h[b], 1);
                    bk[m] = (unsigned char)b;
                    ++m;
                }
            }
        }
    }
    __syncthreads();
    if (tid < nbuk && h[tid]) base[tid] = tid * SLABCAP + atomicAdd(&cursor[tid], h[tid]);
    __syncthreads();
    for (int j2 = 0; j2 < m; ++j2)
        pk_out[base[bk[j2]] + (int)rk[j2]] = pk[j2];
}

// ---------------- CSR build from slabs (counts live in cursor) --------------
__device__ __forceinline__ void csr_body(const unsigned* __restrict__ pk_arr,
                                         const int* __restrict__ cursor,
                                         int* __restrict__ row_ptr,
                                         unsigned short* __restrict__ col_idx,
                                         float* __restrict__ dinv,
                                         int N, int E, int nbuk, int b) {
    __shared__ int hcnt[256];
    __shared__ int esc[256];
    __shared__ int sx[256];
    int tid = threadIdx.x;

    int v = (tid < nbuk) ? cursor[tid] : 0;
    sx[tid] = v;
    __syncthreads();
    int x = v;
    for (int o = 1; o < 256; o <<= 1) {
        int y = (tid >= o) ? sx[tid - o] : 0;
        __syncthreads();
        x += y;
        sx[tid] = x;
        __syncthreads();
    }
    int s0 = (b > 0) ? sx[b - 1] : 0;
    int cnt = sx[b] - s0;
    __syncthreads();

    hcnt[tid] = 0;
    __syncthreads();

    const unsigned* slab = pk_arr + (size_t)b * SLABCAP;
    unsigned p[20];
    unsigned short r[20];
    int m = 0;
    for (int i = tid; i < cnt; i += 256) {
        unsigned pp = slab[i];
        int d = (pp >> 16) & 255;
        r[m] = (unsigned short)atomicAdd(&hcnt[d], 1);
        p[m] = pp;
        ++m;
    }
    __syncthreads();

    int hv = hcnt[tid];
    esc[tid] = hv;
    __syncthreads();
    int hx = hv;
    for (int o = 1; o < 256; o <<= 1) {
        int y = (tid >= o) ? esc[tid - o] : 0;
        __syncthreads();
        hx += y;
        esc[tid] = hx;
        __syncthreads();
    }
    int excl = hx - hv;
    __syncthreads();
    esc[tid] = excl;
    __syncthreads();

    int node = (b << BSH) + tid;
    if (node < N) {
        row_ptr[node] = s0 + excl;
        dinv[node] = rsqrtf((float)(hv + 1));   // +1 self loop
    }
    if (node == N) row_ptr[N] = E;

    for (int j = 0; j < m; ++j) {
        int d = (p[j] >> 16) & 255;
        col_idx[s0 + esc[d] + (int)r[j]] = (unsigned short)(p[j] & 0xFFFFu);
    }
}

// ---------------- GEMM pieces (split-f16 MFMA, prepped fragments) -----------
__device__ __forceinline__ void stage_frags(const _Float16* __restrict__ Whi,
                                            const _Float16* __restrict__ Wlo,
                                            _Float16* __restrict__ WhiS,
                                            _Float16* __restrict__ WloS) {
    const int tid = threadIdx.x;
#pragma unroll
    for (int j = 0; j < 8; ++j)
        ((float4*)WhiS)[tid + j * 256] = ((const float4*)Whi)[tid + j * 256];
#pragma unroll
    for (int j = 0; j < 8; ++j)
        ((float4*)WloS)[tid + j * 256] = ((const float4*)Wlo)[tid + j * 256];
}

template <typename InT>
__device__ __forceinline__ void load_A(const InT* __restrict__ X, int M, int m0,
                                       half8 (&Ahi)[2][4], half8 (&Alo)[2][4]) {
    const int lane = threadIdx.x & 63;
    const int quad = lane >> 4, l16 = lane & 15;
#pragma unroll
    for (int r = 0; r < 2; ++r) {
        int row = m0 + r * 16 + l16;
        row = row < M ? row : (M - 1);
        const InT* xr = X + (size_t)row * 128 + quad * 8;
#pragma unroll
        for (int s = 0; s < 4; ++s) {
            if constexpr (sizeof(InT) == 2) {
                Ahi[r][s] = *(const half8*)(xr + s * 32);   // exact
            } else {
                float4 a = ((const float4*)(xr + s * 32))[0];
                float4 b = ((const float4*)(xr + s * 32))[1];
                float v[8] = {a.x, a.y, a.z, a.w, b.x, b.y, b.z, b.w};
#pragma unroll
                for (int j = 0; j < 8; ++j) {
                    _Float16 hi, lo;
                    split_f16(v[j], hi, lo);
                    Ahi[r][s][j] = hi;
                    Alo[r][s][j] = lo;
                }
            }
        }
    }
}

template <typename OutT, int TERMS, bool BIAS, bool RELU>
__device__ __forceinline__ void mfma_store(half8 (&Ahi)[2][4], half8 (&Alo)[2][4],
                                           const _Float16* __restrict__ WhiS,
                                           const _Float16* __restrict__ WloS,
                                           const float* __restrict__ bias,
                                           OutT* __restrict__ Y, int M, int m0) {
    const int lane = threadIdx.x & 63;
    const int quad = lane >> 4, l16 = lane & 15;

    floatx4 acc[2][8];
#pragma unroll
    for (int r = 0; r < 2; ++r)
#pragma unroll
        for (int t = 0; t < 8; ++t) acc[r][t] = (floatx4){0.f, 0.f, 0.f, 0.f};

    const half8* WH = (const half8*)WhiS;
    const half8* WL = (const half8*)WloS;
#pragma unroll
    for (int s = 0; s < 4; ++s) {
#pragma unroll
        for (int t = 0; t < 8; ++t) {
            half8 bh = WH[(t * 4 + s) * 64 + lane];
            half8 bl = WL[(t * 4 + s) * 64 + lane];
#pragma unroll
            for (int r = 0; r < 2; ++r) {
                acc[r][t] = __builtin_amdgcn_mfma_f32_16x16x32_f16(Ahi[r][s], bh, acc[r][t], 0, 0, 0);
                if constexpr (TERMS == 3)
                    acc[r][t] = __builtin_amdgcn_mfma_f32_16x16x32_f16(Alo[r][s], bh, acc[r][t], 0, 0, 0);
                acc[r][t] = __builtin_amdgcn_mfma_f32_16x16x32_f16(Ahi[r][s], bl, acc[r][t], 0, 0, 0);
            }
        }
    }

    float bcol[8];
    if (BIAS) {
#pragma unroll
        for (int t = 0; t < 8; ++t) bcol[t] = bias[t * 16 + l16];
    }
#pragma unroll
    for (int r = 0; r < 2; ++r) {
#pragma unroll
        for (int e = 0; e < 4; ++e) {
            int row = m0 + r * 16 + quad * 4 + e;
            if (row < M) {
                OutT* yr = Y + (size_t)row * 128 + l16;
#pragma unroll
                for (int t = 0; t < 8; ++t) {
                    float v = acc[r][t][e];
                    if (BIAS) v += bcol[t];
                    if (RELU) v = fmaxf(v, 0.f);
                    if constexpr (sizeof(OutT) == 4) yr[t * 16] = v;
                    else yr[t * 16] = __float2half(v);
                }
            }
        }
    }
}

// ---------------- K2: fused CSR build + layer-0 GEMM ------------------------
__global__ __launch_bounds__(256) void csrgemm_k(const unsigned* __restrict__ pk_arr,
                                                 const int* __restrict__ cursor,
                                                 int* __restrict__ row_ptr,
                                                 unsigned short* __restrict__ col_idx,
                                                 float* __restrict__ dinv,
                                                 const float* __restrict__ X,
                                                 const _Float16* __restrict__ Whi,
                                                 const _Float16* __restrict__ Wlo,
                                                 __half* __restrict__ hs,
                                                 int N, int E, int nbuk) {
    if ((int)blockIdx.x < nbuk) {
        csr_body(pk_arr, cursor, row_ptr, col_idx, dinv, N, E, nbuk, blockIdx.x);
        return;
    }
    __shared__ _Float16 WhiS[16384];
    __shared__ _Float16 WloS[16384];
    stage_frags(Whi, Wlo, WhiS, WloS);
    half8 Ahi[2][4], Alo[2][4];
    int m0 = (blockIdx.x - nbuk) * 128 + ((threadIdx.x >> 6) << 5);
    load_A<float>(X, N, m0, Ahi, Alo);
    __syncthreads();
    mfma_store<__half, 3, false, false>(Ahi, Alo, WhiS, WloS, nullptr, hs, N, m0);
}

// ---------------- K3: fused weighted agg + layer-1 GEMM ---------------------
// Block owns 16 consecutive nodes (one per 16-lane group). Phase 1: weighted
// aggregate (8-deep gather batches, consume-time weight shfl, epilogue bias)
// -> padded LDS f16 tile. Phase 2: 16x128 2-term f16 GEMM, B streamed from
// L2-resident prepped W1 fragments. Output: hs2 (fp16).
#define LP16 136   // f16 elems per LDS row (272B stride -> 2-way banks)
__global__ __launch_bounds__(256, 8) void agg0gemm1_k(const __half* __restrict__ hs,
                                                      const int* __restrict__ row_ptr,
                                                      const unsigned short* __restrict__ col_idx,
                                                      const float* __restrict__ dinv,
                                                      const float* __restrict__ bias,
                                                      const _Float16* __restrict__ W1hi,
                                                      const _Float16* __restrict__ W1lo,
                                                      __half* __restrict__ out_hs, int n) {
    __shared__ _Float16 A[16 * LP16];
    const int tid = threadIdx.x;
    const int c = tid & 15;
    const int g = tid >> 4;
    const int gbase = tid & 48;

    int i = blockIdx.x * 16 + g;

    if (i < n) {
        float di = dinv[i];
        float acc[8];
        {
            uint4 raw = ((const uint4*)(hs + (size_t)i * DFEAT))[c];
            const __half2* hp = (const __half2*)&raw;
#pragma unroll
            for (int k = 0; k < 4; ++k) {
                float2 f = __half22float2(hp[k]);
                acc[2 * k] = f.x * di; acc[2 * k + 1] = f.y * di;
            }
        }
        int s = row_ptr[i];
        int cnt = row_ptr[i + 1] - s;

        for (int base = 0; base < cnt; base += 16) {
            int t = base + c;
            int idx = (t < cnt) ? (int)col_idx[s + t] : 0;
            float dv = (t < cnt) ? dinv[idx] : 0.f;
            int lim = cnt - base; if (lim > 16) lim = 16;
#pragma unroll
            for (int h = 0; h < 2; ++h) {
                int l0 = h * 8;
                if (l0 < lim) {
                    uint4 vv[8];
#pragma unroll
                    for (int q = 0; q < 8; ++q) {
                        int ia = __shfl(idx, gbase + l0 + q);
                        if (l0 + q < lim)
                            vv[q] = ((const uint4*)(hs + (size_t)ia * DFEAT))[c];
                    }
#pragma unroll
                    for (int q = 0; q < 8; ++q) {
                        if (l0 + q < lim) {
                            float wq = __shfl(dv, gbase + l0 + q);
                            const __half2* pq = (const __half2*)&vv[q];
#pragma unroll
                            for (int k = 0; k < 4; ++k) {
                                float2 f = __half22float2(pq[k]);
                                acc[2 * k]     = fmaf(f.x, wq, acc[2 * k]);
                                acc[2 * k + 1] = fmaf(f.y, wq, acc[2 * k + 1]);
                            }
                        }
                    }
                }
            }
        }

        float4 b0 = ((const float4*)bias)[c * 2];
        float4 b1 = ((const float4*)bias)[c * 2 + 1];
        float o[8];
        o[0] = fmaf(acc[0], di, b0.x); o[1] = fmaf(acc[1], di, b0.y);
        o[2] = fmaf(acc[2], di, b0.z); o[3] = fmaf(acc[3], di, b0.w);
        o[4] = fmaf(acc[4], di, b1.x); o[5] = fmaf(acc[5], di, b1.y);
        o[6] = fmaf(acc[6], di, b1.z); o[7] = fmaf(acc[7], di, b1.w);
        _Float16 hv[8];
#pragma unroll
        for (int k = 0; k < 8; ++k) hv[k] = (_Float16)(fmaxf(o[k], 0.f) * di);
        *(uint4*)(&A[g * LP16 + c * 8]) = *(uint4*)hv;
    } else {
        uint4 z = {0u, 0u, 0u, 0u};
        *(uint4*)(&A[g * LP16 + c * 8]) = z;
    }

    __syncthreads();

    // ---- phase 2: GEMM (each wave: 2 column blocks of 16) ----
    const int lane = tid & 63, wave = tid >> 6;
    const int quad = lane >> 4, l16 = lane & 15;
    half8 a[4];
#pragma unroll
    for (int s = 0; s < 4; ++s)
        a[s] = *(const half8*)(&A[l16 * LP16 + s * 32 + quad * 8]);

    floatx4 acc2[2];
    acc2[0] = (floatx4){0.f, 0.f, 0.f, 0.f};
    acc2[1] = (floatx4){0.f, 0.f, 0.f, 0.f};
#pragma unroll
    for (int s = 0; s < 4; ++s) {
#pragma unroll
        for (int tt = 0; tt < 2; ++tt) {
            int t = wave * 2 + tt;
            half8 bh = *(const half8*)(W1hi + ((size_t)((t * 4 + s) * 64 + lane)) * 8);
            half8 bl = *(const half8*)(W1lo + ((size_t)((t * 4 + s) * 64 + lane)) * 8);
            acc2[tt] = __builtin_amdgcn_mfma_f32_16x16x32_f16(a[s], bh, acc2[tt], 0, 0, 0);
            acc2[tt] = __builtin_amdgcn_mfma_f32_16x16x32_f16(a[s], bl, acc2[tt], 0, 0, 0);
        }
    }
#pragma unroll
    for (int tt = 0; tt < 2; ++tt) {
        int col = (wave * 2 + tt) * 16 + l16;
#pragma unroll
        for (int e = 0; e < 4; ++e) {
            int row = blockIdx.x * 16 + quad * 4 + e;
            if (row < n)
                out_hs[(size_t)row * DFEAT + col] = __float2half(acc2[tt][e]);
        }
    }
}

// ---------------- K4: fused plain agg + heads -------------------------------
// Phase 1: unweighted aggregate (8-deep batches, epilogue bias), write out_h
// and stash rows in fp32 LDS tile. Phase 2: head V GEMM, store, then head T
// (sequential -> lower peak VGPR).
#define LP32 132   // f32 elems per LDS row (528B stride -> 2-way banks)
__global__ __launch_bounds__(256, 8) void agg1heads_k(const __half* __restrict__ hs,
                                                      const int* __restrict__ row_ptr,
                                                      const unsigned short* __restrict__ col_idx,
                                                      const float* __restrict__ dinv,
                                                      const float* __restrict__ bias,
                                                      const _Float16* __restrict__ WvHi,
                                                      const _Float16* __restrict__ WvLo,
                                                      const _Float16* __restrict__ WtHi,
                                                      const _Float16* __restrict__ WtLo,
                                                      const float* __restrict__ bv,
                                                      const float* __restrict__ bt,
                                                      float* __restrict__ out_h,
                                                      float* __restrict__ out_v,
                                                      float* __restrict__ out_t, int n) {
    __shared__ float Af[16 * LP32];
    const int tid = threadIdx.x;
    const int c = tid & 15;
    const int g = tid >> 4;
    const int gbase = tid & 48;

    int i = blockIdx.x * 16 + g;

    if (i < n) {
        float acc[8];
        {
            uint4 raw = ((const uint4*)(hs + (size_t)i * DFEAT))[c];
            const __half2* hp = (const __half2*)&raw;
#pragma unroll
            for (int k = 0; k < 4; ++k) {
                float2 f = __half22float2(hp[k]);
                acc[2 * k] = f.x; acc[2 * k + 1] = f.y;
            }
        }
        int s = row_ptr[i];
        int cnt = row_ptr[i + 1] - s;

        for (int base = 0; base < cnt; base += 16) {
            int t = base + c;
            int idx = (t < cnt) ? (int)col_idx[s + t] : 0;
            int lim = cnt - base; if (lim > 16) lim = 16;
#pragma unroll
            for (int h = 0; h < 2; ++h) {
                int l0 = h * 8;
                if (l0 < lim) {
                    uint4 vv[8];
#pragma unroll
                    for (int q = 0; q < 8; ++q) {
                        int ia = __shfl(idx, gbase + l0 + q);
                        if (l0 + q < lim)
                            vv[q] = ((const uint4*)(hs + (size_t)ia * DFEAT))[c];
                    }
#pragma unroll
                    for (int q = 0; q < 8; ++q) {
                        if (l0 + q < lim) {
                            const __half2* pq = (const __half2*)&vv[q];
#pragma unroll
                            for (int k = 0; k < 4; ++k) {
                                float2 f = __half22float2(pq[k]);
                                acc[2 * k]     += f.x;
                                acc[2 * k + 1] += f.y;
                            }
                        }
                    }
                }
            }
        }

        float di = dinv[i];
        float4 b0 = ((const float4*)bias)[c * 2];
        float4 b1 = ((const float4*)bias)[c * 2 + 1];
        float o[8];
        o[0] = fmaf(acc[0], di, b0.x); o[1] = fmaf(acc[1], di, b0.y);
        o[2] = fmaf(acc[2], di, b0.z); o[3] = fmaf(acc[3], di, b0.w);
        o[4] = fmaf(acc[4], di, b1.x); o[5] = fmaf(acc[5], di, b1.y);
        o[6] = fmaf(acc[6], di, b1.z); o[7] = fmaf(acc[7], di, b1.w);
        float4 w0 = make_float4(o[0], o[1], o[2], o[3]);
        float4 w1 = make_float4(o[4], o[5], o[6], o[7]);
        ((float4*)(out_h + (size_t)i * DFEAT))[c * 2] = w0;
        ((float4*)(out_h + (size_t)i * DFEAT))[c * 2 + 1] = w1;
        *(float4*)(&Af[g * LP32 + c * 8]) = w0;
        *(float4*)(&Af[g * LP32 + c * 8 + 4]) = w1;
    } else {
        float4 z = make_float4(0.f, 0.f, 0.f, 0.f);
        *(float4*)(&Af[g * LP32 + c * 8]) = z;
        *(float4*)(&Af[g * LP32 + c * 8 + 4]) = z;
    }

    __syncthreads();

    // ---- phase 2: head GEMMs, sequential (V then T) ----
    const int lane = tid & 63, wave = tid >> 6;
    const int quad = lane >> 4, l16 = lane & 15;
    half8 ahi[4], alo[4];
#pragma unroll
    for (int s = 0; s < 4; ++s) {
        float4 fa = *(const float4*)(&Af[l16 * LP32 + s * 32 + quad * 8]);
        float4 fb = *(const float4*)(&Af[l16 * LP32 + s * 32 + quad * 8 + 4]);
        float v[8] = {fa.x, fa.y, fa.z, fa.w, fb.x, fb.y, fb.z, fb.w};
#pragma unroll
        for (int j = 0; j < 8; ++j) {
            _Float16 hi, lo;
            split_f16(v[j], hi, lo);
            ahi[s][j] = hi;
            alo[s][j] = lo;
        }
    }

    // head V
    {
        floatx4 accV[2];
        accV[0] = (floatx4){0.f, 0.f, 0.f, 0.f};
        accV[1] = (floatx4){0.f, 0.f, 0.f, 0.f};
#pragma unroll
        for (int s = 0; s < 4; ++s) {
#pragma unroll
            for (int tt = 0; tt < 2; ++tt) {
                size_t fi = ((size_t)(((wave * 2 + tt) * 4 + s) * 64 + lane)) * 8;
                half8 bhv = *(const half8*)(WvHi + fi);
                half8 blv = *(const half8*)(WvLo + fi);
                accV[tt] = __builtin_amdgcn_mfma_f32_16x16x32_f16(ahi[s], bhv, accV[tt], 0, 0, 0);
                accV[tt] = __builtin_amdgcn_mfma_f32_16x16x32_f16(alo[s], bhv, accV[tt], 0, 0, 0);
                accV[tt] = __builtin_amdgcn_mfma_f32_16x16x32_f16(ahi[s], blv, accV[tt], 0, 0, 0);
            }
        }
#pragma unroll
        for (int tt = 0; tt < 2; ++tt) {
            int col = (wave * 2 + tt) * 16 + l16;
            float bcv = bv[col];
#pragma unroll
            for (int e = 0; e < 4; ++e) {
                int row = blockIdx.x * 16 + quad * 4 + e;
                if (row < n)
                    out_v[(size_t)row * DFEAT + col] = fmaxf(accV[tt][e] + bcv, 0.f);
            }
        }
    }
    // head T
    {
        floatx4 accT[2];
        accT[0] = (floatx4){0.f, 0.f, 0.f, 0.f};
        accT[1] = (floatx4){0.f, 0.f, 0.f, 0.f};
#pragma unroll
        for (int s = 0; s < 4; ++s) {
#pragma unroll
            for (int tt = 0; tt < 2; ++tt) {
                size_t fi = ((size_t)(((wave * 2 + tt) * 4 + s) * 64 + lane)) * 8;
                half8 bht = *(const half8*)(WtHi + fi);
                half8 blt = *(const half8*)(WtLo + fi);
                accT[tt] = __builtin_amdgcn_mfma_f32_16x16x32_f16(ahi[s], bht, accT[tt], 0, 0, 0);
                accT[tt] = __builtin_amdgcn_mfma_f32_16x16x32_f16(alo[s], bht, accT[tt], 0, 0, 0);
                accT[tt] = __builtin_amdgcn_mfma_f32_16x16x32_f16(ahi[s], blt, accT[tt], 0, 0, 0);
            }
        }
#pragma unroll
        for (int tt = 0; tt < 2; ++tt) {
            int col = (wave * 2 + tt) * 16 + l16;
            float bct = bt[col];
#pragma unroll
            for (int e = 0; e < 4; ++e) {
                int row = blockIdx.x * 16 + quad * 4 + e;
                if (row < n)
                    out_t[(size_t)row * DFEAT + col] = fmaxf(accT[tt][e] + bct, 0.f);
            }
        }
    }
}

// ---------------------------------------------------------------------------

static inline size_t align_up(size_t x, size_t a) { return (x + a - 1) & ~(a - 1); }

extern "C" void kernel_launch(void* const* d_in, const int* in_sizes, int n_in,
                              void* d_out, int out_size, void* d_ws, size_t ws_size,
                              hipStream_t stream) {
    const float* x  = (const float*)d_in[0];
    const int*   ei = (const int*)d_in[1];
    const float* W0 = (const float*)d_in[2];
    const float* b0 = (const float*)d_in[3];
    const float* W1 = (const float*)d_in[4];
    const float* b1 = (const float*)d_in[5];
    const float* Wv = (const float*)d_in[6];
    const float* bv = (const float*)d_in[7];
    const float* Wt = (const float*)d_in[8];
    const float* bt = (const float*)d_in[9];

    const int N = in_sizes[0] / DFEAT;
    const int E = in_sizes[1] / 2;
    const int* src = ei;
    const int* dst = ei + E;
    const int nbuk = (N + 255) >> BSH;
    const int npb  = (E + BKE - 1) / BKE;
    const int gb   = (N + 127) / 128;
    const int fusB = (N + 15) / 16;

    // workspace carve-up
    char* w = (char*)d_ws;
    int* cursor      = (int*)w; w += align_up((size_t)256 * 4, 256);
    unsigned* pk_arr = (unsigned*)w; w += align_up((size_t)nbuk * SLABCAP * 4, 256);
    int* row_ptr     = (int*)w; w += align_up((size_t)(N + 1) * 4, 256);
    unsigned short* col_idx = (unsigned short*)w; w += align_up((size_t)E * 2, 256);
    float* dinv      = (float*)w; w += align_up((size_t)N * 4, 256);
    _Float16* whi_all = (_Float16*)w; w += align_up(4 * 16384 * 2, 256);
    _Float16* wlo_all = (_Float16*)w; w += align_up(4 * 16384 * 2, 256);
    __half* hs       = (__half*)w; w += align_up((size_t)N * DFEAT * 2, 256);
    __half* hs2      = (__half*)w; w += align_up((size_t)N * DFEAT * 2, 256);

    _Float16* w0hi = whi_all;            _Float16* w0lo = wlo_all;
    _Float16* w1hi = whi_all + 16384;    _Float16* w1lo = wlo_all + 16384;
    _Float16* wvhi = whi_all + 2*16384;  _Float16* wvlo = wlo_all + 2*16384;
    _Float16* wthi = whi_all + 3*16384;  _Float16* wtlo = wlo_all + 3*16384;

    float* out_h = (float*)d_out;
    float* out_v = out_h + (size_t)N * DFEAT;
    float* out_t = out_h + 2 * (size_t)N * DFEAT;

    hipMemsetAsync(cursor, 0, 256 * 4, stream);

    // K1: W prep + slab partition
    prep_part_k<<<256 + npb, 256, 0, stream>>>(src, dst, cursor, pk_arr,
                                               W0, W1, Wv, Wt, whi_all, wlo_all,
                                               E, nbuk);
    // K2: CSR build + unscaled layer-0 GEMM (co-resident)
    csrgemm_k<<<nbuk + gb, 256, 0, stream>>>(pk_arr, cursor, row_ptr, col_idx,
                                             dinv, x, w0hi, w0lo, hs, N, E, nbuk);
    // K3: weighted agg + layer-1 GEMM fused -> hs2
    agg0gemm1_k<<<fusB, 256, 0, stream>>>(hs, row_ptr, col_idx, dinv, b0,
                                          w1hi, w1lo, hs2, N);
    // K4: plain agg + both heads fused -> out_h, out_v, out_t
    agg1heads_k<<<fusB, 256, 0, stream>>>(hs2, row_ptr, col_idx, dinv, b1,
                                          wvhi, wvlo, wthi, wtlo, bv, bt,
                                          out_h, out_v, out_t, N);
}